// Round 3
// baseline (757.347 us; speedup 1.0000x reference)
//
#include <hip/hip_runtime.h>

#define B_ 8
#define L_ 512
#define K_ 30
#define H_ 128
#define NIN_ 384
#define MSGW 616   // 584 data + pad-to-608 zeros + 8 align pad
#define BUFW 136   // 128 + 8 pad

typedef __attribute__((ext_vector_type(8))) short short8;
typedef __attribute__((ext_vector_type(8))) unsigned short ushort8;
typedef __attribute__((ext_vector_type(4))) unsigned short us4;
typedef __attribute__((ext_vector_type(4))) float floatx4;
typedef __attribute__((ext_vector_type(4))) float f32x4;

__device__ __forceinline__ float b2f(unsigned short u) {
    union { unsigned int i; float f; } x; x.i = ((unsigned int)u) << 16; return x.f;
}
__device__ __forceinline__ unsigned short f2b(float f) {
    unsigned int u = __builtin_bit_cast(unsigned int, f);
    unsigned int r = (u + 0x7fffu + ((u >> 16) & 1u)) >> 16;
    return (unsigned short)r;
}
__device__ __forceinline__ float gelu_f(float x) {
    return 0.5f * x * (1.0f + erff(x * 0.70710678118654752440f));
}

// ws layout (ushort elements, bf16): W1T[128][608] @0, W2T[128][128] @77824,
// W3T[128][128] @94208, WiT[512][128] @110592, WoT[128][512] @176128. total 241664.
__global__ void prep_kernel(const float* __restrict__ W1,
                            const float* __restrict__ W2,
                            const float* __restrict__ W3,
                            const float* __restrict__ Wi,
                            const float* __restrict__ Wo,
                            unsigned short* __restrict__ ws) {
    int idx = blockIdx.x * 256 + threadIdx.x;
    if (idx < 77824) {
        int n = idx / 608, k = idx % 608;
        ws[idx] = (k < 584) ? f2b(W1[k * 128 + n]) : (unsigned short)0;
    } else if (idx < 94208) {
        int i = idx - 77824; int n = i >> 7, k = i & 127;
        ws[idx] = f2b(W2[k * 128 + n]);
    } else if (idx < 110592) {
        int i = idx - 94208; int n = i >> 7, k = i & 127;
        ws[idx] = f2b(W3[k * 128 + n]);
    } else if (idx < 176128) {
        int i = idx - 110592; int o = i >> 7, c = i & 127;
        ws[idx] = f2b(Wi[c * 512 + o]);
    } else if (idx < 241664) {
        int i = idx - 176128; int c = i >> 9, o = i & 511;
        ws[idx] = f2b(Wo[o * 128 + c]);
    }
}

__global__ __launch_bounds__(256) void main_kernel(
    const float* __restrict__ h_V,
    const float* __restrict__ h_E,
    const float* __restrict__ Xn,
    const float* __restrict__ mask_V,
    const float* __restrict__ mask_attend,
    const float* __restrict__ Wp,
    const float* __restrict__ bp,
    const float* __restrict__ b1g,
    const float* __restrict__ b2g,
    const float* __restrict__ b3g,
    const float* __restrict__ big,
    const float* __restrict__ bog,
    const float* __restrict__ g1,
    const float* __restrict__ be1,
    const float* __restrict__ g2,
    const float* __restrict__ be2,
    const unsigned short* __restrict__ wsT,
    float* __restrict__ out) {

    __shared__ __align__(16) unsigned short msg[32][MSGW];   // bf16 activations
    __shared__ __align__(16) unsigned short buf1[32][BUFW];
    __shared__ float geoR[30][9];
    __shared__ float geoT[30][3];
    __shared__ float geoPl[30][24];
    __shared__ float geoNpg[30][24];
    __shared__ float ploc[24], pglob[24], plnS[8];
    __shared__ float maskA[32];
    __shared__ float nm[128];
    __shared__ float xb[128];
    __shared__ float hS[128];
    __shared__ float gS[512];
    __shared__ float redM[2];

    // buf2 aliases msg storage (msg is dead after MFMA stage 1)
    unsigned short (*buf2)[BUFW] = (unsigned short (*)[BUFW])(&msg[0][0]);

    const int tid  = threadIdx.x;
    const int bl   = blockIdx.x;
    const int wv   = tid >> 6;
    const int lane = tid & 63;
    const int quad = lane >> 4;
    const int l16  = lane & 15;

    const unsigned short* W1T = wsT;
    const unsigned short* W2T = wsT + 77824;
    const unsigned short* W3T = wsT + 94208;
    const unsigned short* WiT = wsT + 110592;
    const unsigned short* WoT = wsT + 176128;

    // ---- phase 1: zero pads, stage h_E / h_V (f32 -> bf16) into msg, frames ----
    {
        ushort8 z = {0, 0, 0, 0, 0, 0, 0, 0};
        // rows 30,31 fully zero (2*616 ushort = 154 vec8)
        for (int i = tid; i < 154; i += 256) ((ushort8*)&msg[30][0])[i] = z;
        // cols 584..615 of rows 0..29
        for (int i = tid; i < 120; i += 256) {
            int k = i >> 2, j = i & 3;
            *(ushort8*)&msg[k][584 + j * 8] = z;
        }
        // h_E (f32) -> msg[k][128..512] as bf16
        const f32x4* src = (const f32x4*)(h_E + (size_t)bl * (K_ * NIN_));
        for (int g = tid; g < (K_ * NIN_) / 4; g += 256) {  // 2880
            int k = g / 96, c4 = g % 96;
            f32x4 v = src[g];
            us4 o;
            o[0] = f2b(v[0]); o[1] = f2b(v[1]); o[2] = f2b(v[2]); o[3] = f2b(v[3]);
            *(us4*)&msg[k][128 + c4 * 4] = o;
        }
        // h_V broadcast -> msg[k][0..128]
        if (tid < 128) {
            unsigned short v = f2b(h_V[bl * 128 + tid]);
            for (int k = 0; k < 30; ++k) msg[k][tid] = v;
        }
        if (tid < 32)
            maskA[tid] = (tid < 30) ? mask_attend[bl * 30 + tid] * (1.0f / 30.0f) : 0.0f;
        // frames: one thread per edge
        if (tid < 30) {
            const float* xp = Xn + ((size_t)bl * 30 + tid) * 9;
            float Nx = xp[0], Ny = xp[1], Nz = xp[2];
            float Ax = xp[3], Ay = xp[4], Az = xp[5];
            float Cx = xp[6], Cy = xp[7], Cz = xp[8];
            float e0x = Ax - Nx, e0y = Ay - Ny, e0z = Az - Nz;
            float r0 = 1.0f / sqrtf(e0x * e0x + e0y * e0y + e0z * e0z + 1e-8f);
            e0x *= r0; e0y *= r0; e0z *= r0;
            float u1x = Cx - Ax, u1y = Cy - Ay, u1z = Cz - Az;
            float d = e0x * u1x + e0y * u1y + e0z * u1z;
            u1x -= e0x * d; u1y -= e0y * d; u1z -= e0z * d;
            float r1 = 1.0f / sqrtf(u1x * u1x + u1y * u1y + u1z * u1z + 1e-8f);
            u1x *= r1; u1y *= r1; u1z *= r1;
            float e2x = e0y * u1z - e0z * u1y;
            float e2y = e0z * u1x - e0x * u1z;
            float e2z = e0x * u1y - e0y * u1x;
            float* Rk = geoR[tid];
            Rk[0] = e0x; Rk[1] = u1x; Rk[2] = e2x;   // R[i][j] = e_j[i]
            Rk[3] = e0y; Rk[4] = u1y; Rk[5] = e2y;
            Rk[6] = e0z; Rk[7] = u1z; Rk[8] = e2z;
            geoT[tid][0] = Ax; geoT[tid][1] = Ay; geoT[tid][2] = Az;
        }
    }
    __syncthreads();

    // ---- phase 2: p_ln = h_V_prev @ Wp + bp  (h_V_prev = msg cols 384..512) ----
    for (int id = tid; id < 720; id += 256) {
        int k = id / 24, c = id % 24;
        float s = bp[c];
        const ushort8* he = (const ushort8*)&msg[k][384];
        const float* wpc = Wp + c;
        for (int c8 = 0; c8 < 16; ++c8) {
            ushort8 v = he[c8];
            const float* w = wpc + c8 * 8 * 24;
            s += b2f(v[0]) * w[0]   + b2f(v[1]) * w[24]  + b2f(v[2]) * w[48]  + b2f(v[3]) * w[72] +
                 b2f(v[4]) * w[96]  + b2f(v[5]) * w[120] + b2f(v[6]) * w[144] + b2f(v[7]) * w[168];
        }
        geoPl[k][c] = s;
    }
    __syncthreads();

    // ---- phase 3: npg = R @ p_ln + t ----
    for (int id = tid; id < 720; id += 256) {
        int k = id / 24, c = id % 24;
        int n3 = (c / 3) * 3, i = c % 3;
        const float* Rk = geoR[k];
        geoNpg[k][c] = Rk[i * 3 + 0] * geoPl[k][n3 + 0] +
                       Rk[i * 3 + 1] * geoPl[k][n3 + 1] +
                       Rk[i * 3 + 2] * geoPl[k][n3 + 2] + geoT[k][i];
    }
    __syncthreads();

    // ---- phase 4: k=0 quantities ----
    if (tid < 24) { ploc[tid] = geoPl[0][tid]; pglob[tid] = geoNpg[0][tid]; }
    else if (tid < 32) {
        int n = tid - 24;
        float a = geoPl[0][n * 3], b = geoPl[0][n * 3 + 1], c = geoPl[0][n * 3 + 2];
        plnS[n] = sqrtf(a * a + b * b + c * c + 1e-8f);
    }
    __syncthreads();

    // ---- phase 5: geometry features -> msg cols 512..584 (bf16) ----
    if (tid < 240) {
        int k = tid >> 3, n = tid & 7;
        const float* R0 = geoR[0];
        const float* t0 = geoT[0];
        float d0 = geoNpg[k][n * 3 + 0] - t0[0];
        float d1 = geoNpg[k][n * 3 + 1] - t0[1];
        float d2 = geoNpg[k][n * 3 + 2] - t0[2];
        float nl0 = R0[0] * d0 + R0[3] * d1 + R0[6] * d2;   // sum_j R0[j][i]*d_j
        float nl1 = R0[1] * d0 + R0[4] * d1 + R0[7] * d2;
        float nl2 = R0[2] * d0 + R0[5] * d1 + R0[8] * d2;
        msg[k][544 + n * 3 + 0] = f2b(nl0);
        msg[k][544 + n * 3 + 1] = f2b(nl1);
        msg[k][544 + n * 3 + 2] = f2b(nl2);
        msg[k][568 + n] = f2b(sqrtf(nl0 * nl0 + nl1 * nl1 + nl2 * nl2 + 1e-8f));
        float q0 = pglob[n * 3 + 0] - geoNpg[k][n * 3 + 0];
        float q1 = pglob[n * 3 + 1] - geoNpg[k][n * 3 + 1];
        float q2 = pglob[n * 3 + 2] - geoNpg[k][n * 3 + 2];
        msg[k][576 + n] = f2b(sqrtf(q0 * q0 + q1 * q1 + q2 * q2 + 1e-8f));
        msg[k][536 + n] = f2b(plnS[n]);
        msg[k][512 + n * 3 + 0] = f2b(ploc[n * 3 + 0]);
        msg[k][512 + n * 3 + 1] = f2b(ploc[n * 3 + 1]);
        msg[k][512 + n * 3 + 2] = f2b(ploc[n * 3 + 2]);
    }
    __syncthreads();

    // ---- stage 1 MFMA: (32 x 608) @ W1T -> gelu -> buf1 ----
    const int c0 = 32 * wv + l16;
    const int c1 = 32 * wv + 16 + l16;
    const int ko = quad * 8;
    {
        floatx4 a00 = {0,0,0,0}, a01 = {0,0,0,0}, a10 = {0,0,0,0}, a11 = {0,0,0,0};
        for (int kc = 0; kc < 19; ++kc) {
            int k0 = kc * 32 + ko;
            short8 fa0 = *(const short8*)&msg[l16][k0];
            short8 fa1 = *(const short8*)&msg[16 + l16][k0];
            short8 fb0 = *(const short8*)(W1T + c0 * 608 + k0);
            short8 fb1 = *(const short8*)(W1T + c1 * 608 + k0);
            a00 = __builtin_amdgcn_mfma_f32_16x16x32_bf16(fa0, fb0, a00, 0, 0, 0);
            a01 = __builtin_amdgcn_mfma_f32_16x16x32_bf16(fa0, fb1, a01, 0, 0, 0);
            a10 = __builtin_amdgcn_mfma_f32_16x16x32_bf16(fa1, fb0, a10, 0, 0, 0);
            a11 = __builtin_amdgcn_mfma_f32_16x16x32_bf16(fa1, fb1, a11, 0, 0, 0);
        }
        float bb0 = b1g[c0], bb1 = b1g[c1];
        for (int r = 0; r < 4; ++r) {
            int r0 = quad * 4 + r, r1 = 16 + quad * 4 + r;
            buf1[r0][c0] = f2b(gelu_f(a00[r] + bb0));
            buf1[r0][c1] = f2b(gelu_f(a01[r] + bb1));
            buf1[r1][c0] = f2b(gelu_f(a10[r] + bb0));
            buf1[r1][c1] = f2b(gelu_f(a11[r] + bb1));
        }
    }
    __syncthreads();

    // ---- stage 2 MFMA: buf1 @ W2T -> gelu -> buf2 (aliases msg) ----
    {
        floatx4 a00 = {0,0,0,0}, a01 = {0,0,0,0}, a10 = {0,0,0,0}, a11 = {0,0,0,0};
        for (int kc = 0; kc < 4; ++kc) {
            int k0 = kc * 32 + ko;
            short8 fa0 = *(const short8*)&buf1[l16][k0];
            short8 fa1 = *(const short8*)&buf1[16 + l16][k0];
            short8 fb0 = *(const short8*)(W2T + c0 * 128 + k0);
            short8 fb1 = *(const short8*)(W2T + c1 * 128 + k0);
            a00 = __builtin_amdgcn_mfma_f32_16x16x32_bf16(fa0, fb0, a00, 0, 0, 0);
            a01 = __builtin_amdgcn_mfma_f32_16x16x32_bf16(fa0, fb1, a01, 0, 0, 0);
            a10 = __builtin_amdgcn_mfma_f32_16x16x32_bf16(fa1, fb0, a10, 0, 0, 0);
            a11 = __builtin_amdgcn_mfma_f32_16x16x32_bf16(fa1, fb1, a11, 0, 0, 0);
        }
        float bb0 = b2g[c0], bb1 = b2g[c1];
        for (int r = 0; r < 4; ++r) {
            int r0 = quad * 4 + r, r1 = 16 + quad * 4 + r;
            buf2[r0][c0] = f2b(gelu_f(a00[r] + bb0));
            buf2[r0][c1] = f2b(gelu_f(a01[r] + bb1));
            buf2[r1][c0] = f2b(gelu_f(a10[r] + bb0));
            buf2[r1][c1] = f2b(gelu_f(a11[r] + bb1));
        }
    }
    __syncthreads();

    // ---- stage 3 MFMA: buf2 @ W3T + b3, mask, mean over k -> nm ----
    {
        floatx4 a00 = {0,0,0,0}, a01 = {0,0,0,0}, a10 = {0,0,0,0}, a11 = {0,0,0,0};
        for (int kc = 0; kc < 4; ++kc) {
            int k0 = kc * 32 + ko;
            short8 fa0 = *(const short8*)&buf2[l16][k0];
            short8 fa1 = *(const short8*)&buf2[16 + l16][k0];
            short8 fb0 = *(const short8*)(W3T + c0 * 128 + k0);
            short8 fb1 = *(const short8*)(W3T + c1 * 128 + k0);
            a00 = __builtin_amdgcn_mfma_f32_16x16x32_bf16(fa0, fb0, a00, 0, 0, 0);
            a01 = __builtin_amdgcn_mfma_f32_16x16x32_bf16(fa0, fb1, a01, 0, 0, 0);
            a10 = __builtin_amdgcn_mfma_f32_16x16x32_bf16(fa1, fb0, a10, 0, 0, 0);
            a11 = __builtin_amdgcn_mfma_f32_16x16x32_bf16(fa1, fb1, a11, 0, 0, 0);
        }
        float bb0 = b3g[c0], bb1 = b3g[c1];
        float cs0 = 0.0f, cs1 = 0.0f;
        for (int r = 0; r < 4; ++r) {
            int r0 = quad * 4 + r, r1 = 16 + quad * 4 + r;
            float m0 = maskA[r0], m1 = maskA[r1];
            cs0 += (a00[r] + bb0) * m0 + (a10[r] + bb0) * m1;
            cs1 += (a01[r] + bb1) * m0 + (a11[r] + bb1) * m1;
        }
        cs0 += __shfl_xor(cs0, 16, 64); cs0 += __shfl_xor(cs0, 32, 64);
        cs1 += __shfl_xor(cs1, 16, 64); cs1 += __shfl_xor(cs1, 32, 64);
        if (lane < 16) { nm[c0] = cs0; nm[c1] = cs1; }
    }
    __syncthreads();

    // ---- LN1 ----
    if (tid < 128) xb[tid] = h_V[bl * 128 + tid] + nm[tid];
    __syncthreads();
    if (wv == 0) {
        float a = xb[lane], b = xb[lane + 64];
        float s = a + b, q = a * a + b * b;
        for (int o = 32; o; o >>= 1) { s += __shfl_xor(s, o, 64); q += __shfl_xor(q, o, 64); }
        if (lane == 0) {
            float m = s * (1.0f / 128.0f);
            redM[0] = m; redM[1] = q * (1.0f / 128.0f) - m * m;
        }
    }
    __syncthreads();
    if (tid < 128) {
        float inv = 1.0f / sqrtf(redM[1] + 1e-5f);
        hS[tid] = (xb[tid] - redM[0]) * inv * g1[tid] + be1[tid];
    }
    __syncthreads();

    // ---- FFN: gelu(h @ Wi + bi) @ Wo + bo ----
    for (int o = tid; o < 512; o += 256) {
        const ushort8* wr = (const ushort8*)(WiT + o * 128);
        float s = big[o];
        for (int c8 = 0; c8 < 16; ++c8) {
            ushort8 v = wr[c8];
            const float* hp = &hS[c8 * 8];
            s += hp[0] * b2f(v[0]) + hp[1] * b2f(v[1]) + hp[2] * b2f(v[2]) + hp[3] * b2f(v[3]) +
                 hp[4] * b2f(v[4]) + hp[5] * b2f(v[5]) + hp[6] * b2f(v[6]) + hp[7] * b2f(v[7]);
        }
        gS[o] = gelu_f(s);
    }
    __syncthreads();
    if (tid < 128) {
        const ushort8* wr = (const ushort8*)(WoT + tid * 512);
        float s = bog[tid];
        for (int o8 = 0; o8 < 64; ++o8) {
            ushort8 v = wr[o8];
            const float* gp = &gS[o8 * 8];
            s += gp[0] * b2f(v[0]) + gp[1] * b2f(v[1]) + gp[2] * b2f(v[2]) + gp[3] * b2f(v[3]) +
                 gp[4] * b2f(v[4]) + gp[5] * b2f(v[5]) + gp[6] * b2f(v[6]) + gp[7] * b2f(v[7]);
        }
        xb[tid] = hS[tid] + s;
    }
    __syncthreads();

    // ---- LN2 + mask_V + store ----
    if (wv == 0) {
        float a = xb[lane], b = xb[lane + 64];
        float s = a + b, q = a * a + b * b;
        for (int o = 32; o; o >>= 1) { s += __shfl_xor(s, o, 64); q += __shfl_xor(q, o, 64); }
        if (lane == 0) {
            float m = s * (1.0f / 128.0f);
            redM[0] = m; redM[1] = q * (1.0f / 128.0f) - m * m;
        }
    }
    __syncthreads();
    if (tid < 128) {
        float inv = 1.0f / sqrtf(redM[1] + 1e-5f);
        float val = (xb[tid] - redM[0]) * inv * g2[tid] + be2[tid];
        val *= mask_V[bl];
        out[bl * 128 + tid] = val;
    }
}

extern "C" void kernel_launch(void* const* d_in, const int* in_sizes, int n_in,
                              void* d_out, int out_size, void* d_ws, size_t ws_size,
                              hipStream_t stream) {
    const float* h_V = (const float*)d_in[0];
    const float* h_E = (const float*)d_in[1];
    // d_in[2] = E_idx (int32, unused by reference)
    const float* Xn  = (const float*)d_in[3];
    const float* mV  = (const float*)d_in[4];
    const float* mA  = (const float*)d_in[5];
    const float* Wp  = (const float*)d_in[6];
    const float* bp  = (const float*)d_in[7];
    const float* W1  = (const float*)d_in[8];
    const float* b1  = (const float*)d_in[9];
    const float* W2  = (const float*)d_in[10];
    const float* b2  = (const float*)d_in[11];
    const float* W3  = (const float*)d_in[12];
    const float* b3  = (const float*)d_in[13];
    const float* Wi  = (const float*)d_in[14];
    const float* bi  = (const float*)d_in[15];
    const float* Wo  = (const float*)d_in[16];
    const float* bo  = (const float*)d_in[17];
    const float* g1  = (const float*)d_in[18];
    const float* be1 = (const float*)d_in[19];
    const float* g2  = (const float*)d_in[20];
    const float* be2 = (const float*)d_in[21];
    unsigned short* ws = (unsigned short*)d_ws;
    float* out = (float*)d_out;

    prep_kernel<<<944, 256, 0, stream>>>(W1, W2, W3, Wi, Wo, ws);
    main_kernel<<<B_ * L_, 256, 0, stream>>>(h_V, h_E, Xn, mV, mA, Wp, bp,
                                             b1, b2, b3, bi, bo,
                                             g1, be1, g2, be2, ws, out);
}

// Round 4
// 603.077 us; speedup vs baseline: 1.2558x; 1.2558x over previous
//
#include <hip/hip_runtime.h>

#define B_ 8
#define L_ 512
#define K_ 30
#define H_ 128
#define NIN_ 384
#define HESTRIDE (K_ * NIN_)   // 11520 floats per (b,l)
#define GEOW 104               // 96 cols (72 data + 24 zero) + 8 pad
#define BUFW 136               // 128 + 8 pad

typedef __attribute__((ext_vector_type(8))) short short8;
typedef __attribute__((ext_vector_type(8))) unsigned short ushort8;
typedef __attribute__((ext_vector_type(4))) float floatx4;
typedef __attribute__((ext_vector_type(4))) float f32x4;

__device__ __forceinline__ float b2f(unsigned short u) {
    union { unsigned int i; float f; } x; x.i = ((unsigned int)u) << 16; return x.f;
}
__device__ __forceinline__ unsigned short f2b(float f) {
    unsigned int u = __builtin_bit_cast(unsigned int, f);
    unsigned int r = (u + 0x7fffu + ((u >> 16) & 1u)) >> 16;
    return (unsigned short)r;
}
__device__ __forceinline__ float gelu_f(float x) {
    return 0.5f * x * (1.0f + erff(x * 0.70710678118654752440f));
}
// pack 8 consecutive f32 at p into a bf16 short8 fragment
__device__ __forceinline__ short8 pack8(const float* p) {
    f32x4 lo = *(const f32x4*)p;
    f32x4 hi = *(const f32x4*)(p + 4);
    short8 r;
    r[0] = (short)f2b(lo[0]); r[1] = (short)f2b(lo[1]);
    r[2] = (short)f2b(lo[2]); r[3] = (short)f2b(lo[3]);
    r[4] = (short)f2b(hi[0]); r[5] = (short)f2b(hi[1]);
    r[6] = (short)f2b(hi[2]); r[7] = (short)f2b(hi[3]);
    return r;
}

// ws layout (ushort elements, bf16):
// W1T[128][608] @0, W2T[128][128] @77824, W3T[128][128] @94208,
// WiT[512][128] @110592, WoT[128][512] @176128, WpT[32][128] @241664. total 245760.
__global__ void prep_kernel(const float* __restrict__ W1,
                            const float* __restrict__ W2,
                            const float* __restrict__ W3,
                            const float* __restrict__ Wi,
                            const float* __restrict__ Wo,
                            const float* __restrict__ Wp,
                            unsigned short* __restrict__ ws) {
    int idx = blockIdx.x * 256 + threadIdx.x;
    if (idx < 77824) {
        int n = idx / 608, k = idx % 608;
        ws[idx] = (k < 584) ? f2b(W1[k * 128 + n]) : (unsigned short)0;
    } else if (idx < 94208) {
        int i = idx - 77824; int n = i >> 7, k = i & 127;
        ws[idx] = f2b(W2[k * 128 + n]);
    } else if (idx < 110592) {
        int i = idx - 94208; int n = i >> 7, k = i & 127;
        ws[idx] = f2b(W3[k * 128 + n]);
    } else if (idx < 176128) {
        int i = idx - 110592; int o = i >> 7, c = i & 127;
        ws[idx] = f2b(Wi[c * 512 + o]);
    } else if (idx < 241664) {
        int i = idx - 176128; int c = i >> 9, o = i & 511;
        ws[idx] = f2b(Wo[o * 128 + c]);
    } else if (idx < 245760) {
        int i = idx - 241664; int c = i >> 7, k = i & 127;
        ws[idx] = (c < 24) ? f2b(Wp[k * 24 + c]) : (unsigned short)0;
    }
}

__global__ __launch_bounds__(256) void main_kernel(
    const float* __restrict__ h_V,
    const float* __restrict__ h_E,
    const float* __restrict__ Xn,
    const float* __restrict__ mask_V,
    const float* __restrict__ mask_attend,
    const float* __restrict__ bp,
    const float* __restrict__ b1g,
    const float* __restrict__ b2g,
    const float* __restrict__ b3g,
    const float* __restrict__ big,
    const float* __restrict__ bog,
    const float* __restrict__ g1,
    const float* __restrict__ be1,
    const float* __restrict__ g2,
    const float* __restrict__ be2,
    const unsigned short* __restrict__ wsT,
    float* __restrict__ out) {

    __shared__ __align__(16) unsigned short buf1[32][BUFW];
    __shared__ __align__(16) union SU {
        struct G {
            unsigned short geoF[32][GEOW];   // bf16 geometry features (stage-1 cols 512..607)
            float R[30][9];
            float T[30][3];
            float Pl[30][24];
            float Npg[30][24];
        } g;
        unsigned short b2buf[32][BUFW];      // stage-2 output, aliases dead geo scratch
    } su;
    __shared__ float maskA[32];
    __shared__ float nm[128];
    __shared__ float xb[128];
    __shared__ float hS[128];
    __shared__ float gS[512];
    __shared__ float ffnP[128];
    __shared__ float redM[2];

    const int tid  = threadIdx.x;
    const int bl   = blockIdx.x;
    const int wv   = tid >> 6;
    const int lane = tid & 63;
    const int quad = lane >> 4;
    const int l16  = lane & 15;
    const int ko   = quad * 8;

    const unsigned short* W1T = wsT;
    const unsigned short* W2T = wsT + 77824;
    const unsigned short* W3T = wsT + 94208;
    const unsigned short* WiT = wsT + 110592;
    const unsigned short* WoT = wsT + 176128;
    const unsigned short* WpT = wsT + 241664;

    const float* hEb = h_E + (size_t)bl * HESTRIDE;

    // ---- phase A: geoF pad zeroing, maskA, frames, p_ln via MFMA ----
    {
        // zero geoF rows 30,31 (cols 0..103) and rows 0..29 cols 72..95
        for (int i = tid; i < 208; i += 256) su.g.geoF[30 + i / GEOW][i % GEOW] = 0;
        for (int i = tid; i < 720; i += 256) su.g.geoF[i / 24][72 + i % 24] = 0;
        if (tid < 32)
            maskA[tid] = (tid < 30) ? mask_attend[bl * 30 + tid] * (1.0f / 30.0f) : 0.0f;
        if (tid < 30) {
            const float* xp = Xn + ((size_t)bl * 30 + tid) * 9;
            float Nx = xp[0], Ny = xp[1], Nz = xp[2];
            float Ax = xp[3], Ay = xp[4], Az = xp[5];
            float Cx = xp[6], Cy = xp[7], Cz = xp[8];
            float e0x = Ax - Nx, e0y = Ay - Ny, e0z = Az - Nz;
            float r0 = 1.0f / sqrtf(e0x * e0x + e0y * e0y + e0z * e0z + 1e-8f);
            e0x *= r0; e0y *= r0; e0z *= r0;
            float u1x = Cx - Ax, u1y = Cy - Ay, u1z = Cz - Az;
            float d = e0x * u1x + e0y * u1y + e0z * u1z;
            u1x -= e0x * d; u1y -= e0y * d; u1z -= e0z * d;
            float r1 = 1.0f / sqrtf(u1x * u1x + u1y * u1y + u1z * u1z + 1e-8f);
            u1x *= r1; u1y *= r1; u1z *= r1;
            float e2x = e0y * u1z - e0z * u1y;
            float e2y = e0z * u1x - e0x * u1z;
            float e2z = e0x * u1y - e0y * u1x;
            float* Rk = su.g.R[tid];
            Rk[0] = e0x; Rk[1] = u1x; Rk[2] = e2x;   // R[i][j] = e_j[i]
            Rk[3] = e0y; Rk[4] = u1y; Rk[5] = e2y;
            Rk[6] = e0z; Rk[7] = u1z; Rk[8] = e2z;
            su.g.T[tid][0] = Ax; su.g.T[tid][1] = Ay; su.g.T[tid][2] = Az;
        }
        // p_ln = h_V_prev @ Wp + bp via MFMA: A = h_E cols 256..384 (rows = edges)
        int rt = wv >> 1, ct = wv & 1;           // row-tile, col-tile per wave
        floatx4 acc = {0, 0, 0, 0};
        for (int kc = 0; kc < 4; ++kc) {
            int col = 256 + kc * 32 + ko;
            int row = rt * 16 + l16;
            int valid = row < 30;
            short8 fa = pack8(hEb + (valid ? row : 0) * NIN_ + col);
            if (!valid) fa = (short8){0,0,0,0,0,0,0,0};
            short8 fb = *(const short8*)(WpT + (ct * 16 + l16) * 128 + kc * 32 + ko);
            acc = __builtin_amdgcn_mfma_f32_16x16x32_bf16(fa, fb, acc, 0, 0, 0);
        }
        int ccol = ct * 16 + l16;
        if (ccol < 24) {
            float bpc = bp[ccol];
            for (int i = 0; i < 4; ++i) {
                int row = rt * 16 + quad * 4 + i;
                if (row < 30) su.g.Pl[row][ccol] = acc[i] + bpc;
            }
        }
    }
    __syncthreads();

    // ---- phase B: npg = R @ p_ln + t ----
    for (int id = tid; id < 720; id += 256) {
        int k = id / 24, c = id % 24;
        int n3 = (c / 3) * 3, i = c % 3;
        const float* Rk = su.g.R[k];
        su.g.Npg[k][c] = Rk[i * 3 + 0] * su.g.Pl[k][n3 + 0] +
                         Rk[i * 3 + 1] * su.g.Pl[k][n3 + 1] +
                         Rk[i * 3 + 2] * su.g.Pl[k][n3 + 2] + su.g.T[k][i];
    }
    __syncthreads();

    // ---- phase C: geometry features -> geoF cols 0..71 (bf16) ----
    // col map: [0..23]=ple, [24..31]=pln, [32..55]=npl, [56..63]=npl_norm, [64..71]=npg_norm
    if (tid < 240) {
        int k = tid >> 3, n = tid & 7;
        const float* R0 = su.g.R[0];
        const float* t0 = su.g.T[0];
        float p0 = su.g.Pl[0][n * 3], p1 = su.g.Pl[0][n * 3 + 1], p2 = su.g.Pl[0][n * 3 + 2];
        float g0 = su.g.Npg[0][n * 3], g1v = su.g.Npg[0][n * 3 + 1], g2v = su.g.Npg[0][n * 3 + 2];
        float a0 = su.g.Npg[k][n * 3], a1 = su.g.Npg[k][n * 3 + 1], a2 = su.g.Npg[k][n * 3 + 2];
        float d0 = a0 - t0[0], d1 = a1 - t0[1], d2 = a2 - t0[2];
        float nl0 = R0[0] * d0 + R0[3] * d1 + R0[6] * d2;   // R0^T @ d
        float nl1 = R0[1] * d0 + R0[4] * d1 + R0[7] * d2;
        float nl2 = R0[2] * d0 + R0[5] * d1 + R0[8] * d2;
        unsigned short* gf = su.g.geoF[k];
        gf[0  + n * 3] = f2b(p0); gf[1  + n * 3] = f2b(p1); gf[2  + n * 3] = f2b(p2);
        gf[24 + n] = f2b(sqrtf(p0 * p0 + p1 * p1 + p2 * p2 + 1e-8f));
        gf[32 + n * 3] = f2b(nl0); gf[33 + n * 3] = f2b(nl1); gf[34 + n * 3] = f2b(nl2);
        gf[56 + n] = f2b(sqrtf(nl0 * nl0 + nl1 * nl1 + nl2 * nl2 + 1e-8f));
        float q0 = g0 - a0, q1 = g1v - a1, q2 = g2v - a2;
        gf[64 + n] = f2b(sqrtf(q0 * q0 + q1 * q1 + q2 * q2 + 1e-8f));
    }
    __syncthreads();

    // ---- stage 1 MFMA: [32 x 608] @ W1T -> gelu -> buf1 ----
    const int c0 = 32 * wv + l16;
    const int c1 = c0 + 16;
    {
        floatx4 a00 = {0,0,0,0}, a01 = {0,0,0,0}, a10 = {0,0,0,0}, a11 = {0,0,0,0};
        const unsigned short* wb0 = W1T + c0 * 608;
        const unsigned short* wb1 = W1T + c1 * 608;
        // segment 1: h_V (k rows 0..127) — identical across A rows
        for (int kc = 0; kc < 4; ++kc) {
            int col = kc * 32 + ko;
            short8 fa = pack8(h_V + bl * 128 + col);
            short8 fb0 = *(const short8*)(wb0 + col);
            short8 fb1 = *(const short8*)(wb1 + col);
            a00 = __builtin_amdgcn_mfma_f32_16x16x32_bf16(fa, fb0, a00, 0, 0, 0);
            a01 = __builtin_amdgcn_mfma_f32_16x16x32_bf16(fa, fb1, a01, 0, 0, 0);
            a10 = __builtin_amdgcn_mfma_f32_16x16x32_bf16(fa, fb0, a10, 0, 0, 0);
            a11 = __builtin_amdgcn_mfma_f32_16x16x32_bf16(fa, fb1, a11, 0, 0, 0);
        }
        // segment 2: h_E (k rows 128..511), A rows = edge index
        for (int kc = 0; kc < 12; ++kc) {
            int col = kc * 32 + ko;
            short8 fa0 = pack8(hEb + l16 * NIN_ + col);
            int r1 = 16 + l16;
            int valid = r1 < 30;
            short8 fa1 = pack8(hEb + (valid ? r1 : 0) * NIN_ + col);
            if (!valid) fa1 = (short8){0,0,0,0,0,0,0,0};
            short8 fb0 = *(const short8*)(wb0 + 128 + col);
            short8 fb1 = *(const short8*)(wb1 + 128 + col);
            a00 = __builtin_amdgcn_mfma_f32_16x16x32_bf16(fa0, fb0, a00, 0, 0, 0);
            a01 = __builtin_amdgcn_mfma_f32_16x16x32_bf16(fa0, fb1, a01, 0, 0, 0);
            a10 = __builtin_amdgcn_mfma_f32_16x16x32_bf16(fa1, fb0, a10, 0, 0, 0);
            a11 = __builtin_amdgcn_mfma_f32_16x16x32_bf16(fa1, fb1, a11, 0, 0, 0);
        }
        // segment 3: geometry features (k rows 512..607) from LDS
        for (int kc = 0; kc < 3; ++kc) {
            int col = kc * 32 + ko;
            short8 fa0 = *(const short8*)&su.g.geoF[l16][col];
            short8 fa1 = *(const short8*)&su.g.geoF[16 + l16][col];
            short8 fb0 = *(const short8*)(wb0 + 512 + col);
            short8 fb1 = *(const short8*)(wb1 + 512 + col);
            a00 = __builtin_amdgcn_mfma_f32_16x16x32_bf16(fa0, fb0, a00, 0, 0, 0);
            a01 = __builtin_amdgcn_mfma_f32_16x16x32_bf16(fa0, fb1, a01, 0, 0, 0);
            a10 = __builtin_amdgcn_mfma_f32_16x16x32_bf16(fa1, fb0, a10, 0, 0, 0);
            a11 = __builtin_amdgcn_mfma_f32_16x16x32_bf16(fa1, fb1, a11, 0, 0, 0);
        }
        float bb0 = b1g[c0], bb1 = b1g[c1];
        for (int r = 0; r < 4; ++r) {
            int r0 = quad * 4 + r, r1 = 16 + quad * 4 + r;
            buf1[r0][c0] = f2b(gelu_f(a00[r] + bb0));
            buf1[r0][c1] = f2b(gelu_f(a01[r] + bb1));
            buf1[r1][c0] = f2b(gelu_f(a10[r] + bb0));
            buf1[r1][c1] = f2b(gelu_f(a11[r] + bb1));
        }
    }
    __syncthreads();

    // ---- stage 2 MFMA: buf1 @ W2T -> gelu -> b2buf (aliases geo scratch) ----
    {
        floatx4 a00 = {0,0,0,0}, a01 = {0,0,0,0}, a10 = {0,0,0,0}, a11 = {0,0,0,0};
        for (int kc = 0; kc < 4; ++kc) {
            int k0 = kc * 32 + ko;
            short8 fa0 = *(const short8*)&buf1[l16][k0];
            short8 fa1 = *(const short8*)&buf1[16 + l16][k0];
            short8 fb0 = *(const short8*)(W2T + c0 * 128 + k0);
            short8 fb1 = *(const short8*)(W2T + c1 * 128 + k0);
            a00 = __builtin_amdgcn_mfma_f32_16x16x32_bf16(fa0, fb0, a00, 0, 0, 0);
            a01 = __builtin_amdgcn_mfma_f32_16x16x32_bf16(fa0, fb1, a01, 0, 0, 0);
            a10 = __builtin_amdgcn_mfma_f32_16x16x32_bf16(fa1, fb0, a10, 0, 0, 0);
            a11 = __builtin_amdgcn_mfma_f32_16x16x32_bf16(fa1, fb1, a11, 0, 0, 0);
        }
        float bb0 = b2g[c0], bb1 = b2g[c1];
        for (int r = 0; r < 4; ++r) {
            int r0 = quad * 4 + r, r1 = 16 + quad * 4 + r;
            su.b2buf[r0][c0] = f2b(gelu_f(a00[r] + bb0));
            su.b2buf[r0][c1] = f2b(gelu_f(a01[r] + bb1));
            su.b2buf[r1][c0] = f2b(gelu_f(a10[r] + bb0));
            su.b2buf[r1][c1] = f2b(gelu_f(a11[r] + bb1));
        }
    }
    __syncthreads();

    // ---- stage 3 MFMA: b2buf @ W3T + b3, mask, mean over k -> nm ----
    {
        floatx4 a00 = {0,0,0,0}, a01 = {0,0,0,0}, a10 = {0,0,0,0}, a11 = {0,0,0,0};
        for (int kc = 0; kc < 4; ++kc) {
            int k0 = kc * 32 + ko;
            short8 fa0 = *(const short8*)&su.b2buf[l16][k0];
            short8 fa1 = *(const short8*)&su.b2buf[16 + l16][k0];
            short8 fb0 = *(const short8*)(W3T + c0 * 128 + k0);
            short8 fb1 = *(const short8*)(W3T + c1 * 128 + k0);
            a00 = __builtin_amdgcn_mfma_f32_16x16x32_bf16(fa0, fb0, a00, 0, 0, 0);
            a01 = __builtin_amdgcn_mfma_f32_16x16x32_bf16(fa0, fb1, a01, 0, 0, 0);
            a10 = __builtin_amdgcn_mfma_f32_16x16x32_bf16(fa1, fb0, a10, 0, 0, 0);
            a11 = __builtin_amdgcn_mfma_f32_16x16x32_bf16(fa1, fb1, a11, 0, 0, 0);
        }
        float bb0 = b3g[c0], bb1 = b3g[c1];
        float cs0 = 0.0f, cs1 = 0.0f;
        for (int r = 0; r < 4; ++r) {
            int r0 = quad * 4 + r, r1 = 16 + quad * 4 + r;
            float m0 = maskA[r0], m1 = maskA[r1];
            cs0 += (a00[r] + bb0) * m0 + (a10[r] + bb0) * m1;
            cs1 += (a01[r] + bb1) * m0 + (a11[r] + bb1) * m1;
        }
        cs0 += __shfl_xor(cs0, 16, 64); cs0 += __shfl_xor(cs0, 32, 64);
        cs1 += __shfl_xor(cs1, 16, 64); cs1 += __shfl_xor(cs1, 32, 64);
        if (lane < 16) { nm[c0] = cs0; nm[c1] = cs1; }
    }
    __syncthreads();

    // ---- LN1 ----
    if (tid < 128) xb[tid] = h_V[bl * 128 + tid] + nm[tid];
    __syncthreads();
    if (wv == 0) {
        float a = xb[lane], b = xb[lane + 64];
        float s = a + b, q = a * a + b * b;
        for (int o = 32; o; o >>= 1) { s += __shfl_xor(s, o, 64); q += __shfl_xor(q, o, 64); }
        if (lane == 0) {
            float m = s * (1.0f / 128.0f);
            redM[0] = m; redM[1] = q * (1.0f / 128.0f) - m * m;
        }
    }
    __syncthreads();
    if (tid < 128) {
        float inv = 1.0f / sqrtf(redM[1] + 1e-5f);
        hS[tid] = (xb[tid] - redM[0]) * inv * g1[tid] + be1[tid];
    }
    __syncthreads();

    // ---- FFN1: gelu(h @ Wi + bi) -> gS ----
    for (int o = tid; o < 512; o += 256) {
        const ushort8* wr = (const ushort8*)(WiT + o * 128);
        float s = big[o];
        for (int c8 = 0; c8 < 16; ++c8) {
            ushort8 v = wr[c8];
            const float* hp = &hS[c8 * 8];
            s += hp[0] * b2f(v[0]) + hp[1] * b2f(v[1]) + hp[2] * b2f(v[2]) + hp[3] * b2f(v[3]) +
                 hp[4] * b2f(v[4]) + hp[5] * b2f(v[5]) + hp[6] * b2f(v[6]) + hp[7] * b2f(v[7]);
        }
        gS[o] = gelu_f(s);
    }
    __syncthreads();

    // ---- FFN2: gS @ Wo + bo, split halves over 256 threads ----
    {
        int c = tid & 127, half = tid >> 7;
        const ushort8* wr = (const ushort8*)(WoT + c * 512 + half * 256);
        float s = half ? 0.0f : bog[c];
        const float* gb = &gS[half * 256];
        for (int o8 = 0; o8 < 32; ++o8) {
            ushort8 v = wr[o8];
            const float* gp = gb + o8 * 8;
            s += gp[0] * b2f(v[0]) + gp[1] * b2f(v[1]) + gp[2] * b2f(v[2]) + gp[3] * b2f(v[3]) +
                 gp[4] * b2f(v[4]) + gp[5] * b2f(v[5]) + gp[6] * b2f(v[6]) + gp[7] * b2f(v[7]);
        }
        if (half) ffnP[c] = s;
        __syncthreads();
        if (tid < 128) xb[tid] = hS[tid] + s + ffnP[tid];
    }
    __syncthreads();

    // ---- LN2 + mask_V + store ----
    if (wv == 0) {
        float a = xb[lane], b = xb[lane + 64];
        float s = a + b, q = a * a + b * b;
        for (int o = 32; o; o >>= 1) { s += __shfl_xor(s, o, 64); q += __shfl_xor(q, o, 64); }
        if (lane == 0) {
            float m = s * (1.0f / 128.0f);
            redM[0] = m; redM[1] = q * (1.0f / 128.0f) - m * m;
        }
    }
    __syncthreads();
    if (tid < 128) {
        float inv = 1.0f / sqrtf(redM[1] + 1e-5f);
        float val = (xb[tid] - redM[0]) * inv * g2[tid] + be2[tid];
        val *= mask_V[bl];
        out[bl * 128 + tid] = val;
    }
}

extern "C" void kernel_launch(void* const* d_in, const int* in_sizes, int n_in,
                              void* d_out, int out_size, void* d_ws, size_t ws_size,
                              hipStream_t stream) {
    const float* h_V = (const float*)d_in[0];
    const float* h_E = (const float*)d_in[1];
    // d_in[2] = E_idx (int32, unused by reference)
    const float* Xn  = (const float*)d_in[3];
    const float* mV  = (const float*)d_in[4];
    const float* mA  = (const float*)d_in[5];
    const float* Wp  = (const float*)d_in[6];
    const float* bp  = (const float*)d_in[7];
    const float* W1  = (const float*)d_in[8];
    const float* b1  = (const float*)d_in[9];
    const float* W2  = (const float*)d_in[10];
    const float* b2  = (const float*)d_in[11];
    const float* W3  = (const float*)d_in[12];
    const float* b3  = (const float*)d_in[13];
    const float* Wi  = (const float*)d_in[14];
    const float* bi  = (const float*)d_in[15];
    const float* Wo  = (const float*)d_in[16];
    const float* bo  = (const float*)d_in[17];
    const float* g1  = (const float*)d_in[18];
    const float* be1 = (const float*)d_in[19];
    const float* g2  = (const float*)d_in[20];
    const float* be2 = (const float*)d_in[21];
    unsigned short* ws = (unsigned short*)d_ws;
    float* out = (float*)d_out;

    prep_kernel<<<960, 256, 0, stream>>>(W1, W2, W3, Wi, Wo, Wp, ws);
    main_kernel<<<B_ * L_, 256, 0, stream>>>(h_V, h_E, Xn, mV, mA, bp,
                                             b1, b2, b3, bi, bo,
                                             g1, be1, g2, be2, ws, out);
}

// Round 5
// 566.132 us; speedup vs baseline: 1.3378x; 1.0653x over previous
//
#include <hip/hip_runtime.h>

#define B_ 8
#define L_ 512
#define K_ 30
#define NIN_ 384
#define HES 11520          // floats per site in h_E
#define BUFW 136           // buf1 row stride (ushort), 272B = 17*16 aligned
#define GFW 104            // geoF row stride (ushort), 208B: conflict-free-ish
#define PW 7680            // ushorts per wave of LDS (15360 B)

typedef __attribute__((ext_vector_type(8))) short short8;
typedef __attribute__((ext_vector_type(8))) unsigned short ushort8;
typedef __attribute__((ext_vector_type(4))) float floatx4;
typedef __attribute__((ext_vector_type(4))) float f32x4;

__device__ __forceinline__ float b2f(unsigned short u) {
    union { unsigned int i; float f; } x; x.i = ((unsigned int)u) << 16; return x.f;
}
__device__ __forceinline__ unsigned short f2b(float f) {
    unsigned int u = __builtin_bit_cast(unsigned int, f);
    return (unsigned short)((u + 0x7fffu + ((u >> 16) & 1u)) >> 16);
}
__device__ __forceinline__ float gelu_f(float x) {
    return 0.5f * x * (1.0f + erff(x * 0.70710678118654752440f));
}
__device__ __forceinline__ short8 pack8(const float* p) {
    f32x4 lo = *(const f32x4*)p;
    f32x4 hi = *(const f32x4*)(p + 4);
    short8 r;
    r[0] = (short)f2b(lo[0]); r[1] = (short)f2b(lo[1]);
    r[2] = (short)f2b(lo[2]); r[3] = (short)f2b(lo[3]);
    r[4] = (short)f2b(hi[0]); r[5] = (short)f2b(hi[1]);
    r[6] = (short)f2b(hi[2]); r[7] = (short)f2b(hi[3]);
    return r;
}

// ws layout (ushort, bf16): W1T[128][608]@0, W2T[128][128]@77824, W3T[128][128]@94208,
// WiT[512][128]@110592, WoT[128][512]@176128, WpT[32][128]@241664. total 245760.
// All reads coalesced (inner index = contiguous input dim); writes scattered (L2-absorbed).
__global__ void prep_kernel(const float* __restrict__ W1,
                            const float* __restrict__ W2,
                            const float* __restrict__ W3,
                            const float* __restrict__ Wi,
                            const float* __restrict__ Wo,
                            const float* __restrict__ Wp,
                            unsigned short* __restrict__ ws) {
    int idx = blockIdx.x * 256 + threadIdx.x;
    if (idx < 77824) {
        int n = idx & 127, k = idx >> 7;                 // k < 608
        ws[n * 608 + k] = (k < 584) ? f2b(W1[k * 128 + n]) : (unsigned short)0;
    } else if (idx < 94208) {
        int i = idx - 77824; int n = i & 127, k = i >> 7;
        ws[77824 + n * 128 + k] = f2b(W2[k * 128 + n]);
    } else if (idx < 110592) {
        int i = idx - 94208; int n = i & 127, k = i >> 7;
        ws[94208 + n * 128 + k] = f2b(W3[k * 128 + n]);
    } else if (idx < 176128) {
        int i = idx - 110592; int o = i & 511, c = i >> 9;
        ws[110592 + o * 128 + c] = f2b(Wi[c * 512 + o]);
    } else if (idx < 241664) {
        int i = idx - 176128; int c = i & 127, o = i >> 7;
        ws[176128 + c * 512 + o] = f2b(Wo[o * 128 + c]);
    } else if (idx < 245760) {
        int i = idx - 241664; int k = i & 127, c = i >> 7;  // c < 32
        ws[241664 + c * 128 + k] = (c < 24) ? f2b(Wp[k * 24 + c]) : (unsigned short)0;
    }
}

// One wave per (b,l) site. NO __syncthreads anywhere: all LDS is wave-private,
// RAW handled by compiler lgkmcnt within the wave's program order.
__global__ __launch_bounds__(128, 2) void main_kernel(
    const float* __restrict__ h_V,
    const float* __restrict__ h_E,
    const float* __restrict__ Xn,
    const float* __restrict__ mask_V,
    const float* __restrict__ mask_attend,
    const float* __restrict__ bp,
    const float* __restrict__ b1g,
    const float* __restrict__ b2g,
    const float* __restrict__ b3g,
    const float* __restrict__ big,
    const float* __restrict__ bog,
    const float* __restrict__ g1,
    const float* __restrict__ be1,
    const float* __restrict__ g2,
    const float* __restrict__ be2,
    const unsigned short* __restrict__ wsT,
    float* __restrict__ out) {

    __shared__ __align__(16) unsigned short lds[2 * PW];

    const int tid  = threadIdx.x;
    const int wv   = tid >> 6;
    const int lane = tid & 63;
    const int quad = lane >> 4;
    const int l16  = lane & 15;
    const int ko   = quad * 8;
    const int site = blockIdx.x * 2 + wv;

    unsigned short* wl   = lds + wv * PW;
    unsigned short* buf1 = wl;                    // [32][BUFW] bf16 (also geo-f32 / tail-f32 overlay)
    float*          G    = (float*)wl;            // geo: R@0(270), T@270(90), Pl@360(720), Npg@1080(720)
    unsigned short* geoF = wl + 4352;             // [32][GFW] bf16
    float*          F    = (float*)wl;            // tail: hS@0..127, gS@128..639, nm@640..767

    const unsigned short* W1T = wsT;
    const unsigned short* W2T = wsT + 77824;
    const unsigned short* W3T = wsT + 94208;
    const unsigned short* WiT = wsT + 110592;
    const unsigned short* WoT = wsT + 176128;
    const unsigned short* WpT = wsT + 241664;

    const float* hEb = h_E + (size_t)site * HES;
    const float* hVb = h_V + site * 128;
    const short8 z8 = {0, 0, 0, 0, 0, 0, 0, 0};

    // mask (scaled by 1/30) for this lane's C-layout rows
    float maskR[2][4];
    for (int rt = 0; rt < 2; ++rt)
        for (int r = 0; r < 4; ++r) {
            int row = rt * 16 + quad * 4 + r;
            maskR[rt][r] = (row < K_) ? mask_attend[site * K_ + row] * (1.0f / 30.0f) : 0.0f;
        }

    // ---- geoF zero (rows 30,31 and pad cols stay zero) ----
    for (int i = lane; i < (32 * GFW) / 8; i += 64) ((short8*)geoF)[i] = z8;

    // ---- frames (lanes 0..29) ----
    if (lane < K_) {
        const float* xp = Xn + ((size_t)site * K_ + lane) * 9;
        float Nx = xp[0], Ny = xp[1], Nz = xp[2];
        float Ax = xp[3], Ay = xp[4], Az = xp[5];
        float Cx = xp[6], Cy = xp[7], Cz = xp[8];
        float e0x = Ax - Nx, e0y = Ay - Ny, e0z = Az - Nz;
        float r0 = 1.0f / sqrtf(e0x * e0x + e0y * e0y + e0z * e0z + 1e-8f);
        e0x *= r0; e0y *= r0; e0z *= r0;
        float u1x = Cx - Ax, u1y = Cy - Ay, u1z = Cz - Az;
        float d = e0x * u1x + e0y * u1y + e0z * u1z;
        u1x -= e0x * d; u1y -= e0y * d; u1z -= e0z * d;
        float r1 = 1.0f / sqrtf(u1x * u1x + u1y * u1y + u1z * u1z + 1e-8f);
        u1x *= r1; u1y *= r1; u1z *= r1;
        float e2x = e0y * u1z - e0z * u1y;
        float e2y = e0z * u1x - e0x * u1z;
        float e2z = e0x * u1y - e0y * u1x;
        float* Rk = G + lane * 9;                 // R[i][j] = e_j[i]
        Rk[0] = e0x; Rk[1] = u1x; Rk[2] = e2x;
        Rk[3] = e0y; Rk[4] = u1y; Rk[5] = e2y;
        Rk[6] = e0z; Rk[7] = u1z; Rk[8] = e2z;
        G[270 + lane * 3 + 0] = Ax; G[270 + lane * 3 + 1] = Ay; G[270 + lane * 3 + 2] = Az;
    }

    // ---- p_ln = h_V_prev @ Wp + bp (MFMA, A = h_E cols 256..383) ----
    {
        floatx4 a[2][2] = {{{0,0,0,0},{0,0,0,0}},{{0,0,0,0},{0,0,0,0}}};
        for (int kc = 0; kc < 4; ++kc) {
            int col = 256 + kc * 32 + ko;
            short8 fa0 = pack8(hEb + l16 * NIN_ + col);
            int r1 = 16 + l16;
            short8 fa1 = (r1 < K_) ? pack8(hEb + r1 * NIN_ + col) : z8;
            for (int ct = 0; ct < 2; ++ct) {
                short8 fb = *(const short8*)(WpT + (ct * 16 + l16) * 128 + kc * 32 + ko);
                a[0][ct] = __builtin_amdgcn_mfma_f32_16x16x32_bf16(fa0, fb, a[0][ct], 0, 0, 0);
                a[1][ct] = __builtin_amdgcn_mfma_f32_16x16x32_bf16(fa1, fb, a[1][ct], 0, 0, 0);
            }
        }
        for (int ct = 0; ct < 2; ++ct) {
            int ccol = ct * 16 + l16;
            if (ccol < 24) {
                float bpc = bp[ccol];
                for (int rt = 0; rt < 2; ++rt)
                    for (int i = 0; i < 4; ++i) {
                        int row = rt * 16 + quad * 4 + i;
                        if (row < K_) G[360 + row * 24 + ccol] = a[rt][ct][i] + bpc;
                    }
            }
        }
    }

    // ---- npg = R @ p_ln + t ----
    for (int id = lane; id < 720; id += 64) {
        int k = id / 24, c = id % 24;
        int n3 = (c / 3) * 3, i = c % 3;
        const float* Rk = G + k * 9;
        G[1080 + k * 24 + c] = Rk[i * 3 + 0] * G[360 + k * 24 + n3 + 0] +
                               Rk[i * 3 + 1] * G[360 + k * 24 + n3 + 1] +
                               Rk[i * 3 + 2] * G[360 + k * 24 + n3 + 2] + G[270 + k * 3 + i];
    }

    // ---- features -> geoF cols: ple@0, pln@24, npl@32, npl_norm@56, npg_norm@64 ----
    for (int id = lane; id < 240; id += 64) {
        int k = id >> 3, n = id & 7;
        const float* R0 = G;
        const float* t0 = G + 270;
        float p0 = G[360 + n * 3], p1 = G[360 + n * 3 + 1], p2 = G[360 + n * 3 + 2];
        float q0g = G[1080 + n * 3], q1g = G[1080 + n * 3 + 1], q2g = G[1080 + n * 3 + 2];
        float a0 = G[1080 + k * 24 + n * 3], a1 = G[1080 + k * 24 + n * 3 + 1], a2 = G[1080 + k * 24 + n * 3 + 2];
        float d0 = a0 - t0[0], d1 = a1 - t0[1], d2 = a2 - t0[2];
        float nl0 = R0[0] * d0 + R0[3] * d1 + R0[6] * d2;
        float nl1 = R0[1] * d0 + R0[4] * d1 + R0[7] * d2;
        float nl2 = R0[2] * d0 + R0[5] * d1 + R0[8] * d2;
        unsigned short* gf = geoF + k * GFW;
        gf[0 + n * 3] = f2b(p0); gf[1 + n * 3] = f2b(p1); gf[2 + n * 3] = f2b(p2);
        gf[24 + n] = f2b(sqrtf(p0 * p0 + p1 * p1 + p2 * p2 + 1e-8f));
        gf[32 + n * 3] = f2b(nl0); gf[33 + n * 3] = f2b(nl1); gf[34 + n * 3] = f2b(nl2);
        gf[56 + n] = f2b(sqrtf(nl0 * nl0 + nl1 * nl1 + nl2 * nl2 + 1e-8f));
        float q0 = q0g - a0, q1 = q1g - a1, q2 = q2g - a2;
        gf[64 + n] = f2b(sqrtf(q0 * q0 + q1 * q1 + q2 * q2 + 1e-8f));
    }

    // ---- stage 1: [32 x 608] @ W1T -> gelu -> buf1 (full N=128 per wave) ----
    {
        floatx4 acc[2][8];
        for (int rt = 0; rt < 2; ++rt) for (int ct = 0; ct < 8; ++ct) acc[rt][ct] = (floatx4){0,0,0,0};
        for (int kc = 0; kc < 4; ++kc) {            // seg1: h_V (rows identical)
            int col = kc * 32 + ko;
            short8 fa = pack8(hVb + col);
            for (int ct = 0; ct < 8; ++ct) {
                short8 fb = *(const short8*)(W1T + (ct * 16 + l16) * 608 + col);
                acc[0][ct] = __builtin_amdgcn_mfma_f32_16x16x32_bf16(fa, fb, acc[0][ct], 0, 0, 0);
                acc[1][ct] = __builtin_amdgcn_mfma_f32_16x16x32_bf16(fa, fb, acc[1][ct], 0, 0, 0);
            }
        }
        for (int kc = 0; kc < 12; ++kc) {           // seg2: h_E
            int col = kc * 32 + ko;
            short8 fa0 = pack8(hEb + l16 * NIN_ + col);
            int r1 = 16 + l16;
            short8 fa1 = (r1 < K_) ? pack8(hEb + r1 * NIN_ + col) : z8;
            for (int ct = 0; ct < 8; ++ct) {
                short8 fb = *(const short8*)(W1T + (ct * 16 + l16) * 608 + 128 + col);
                acc[0][ct] = __builtin_amdgcn_mfma_f32_16x16x32_bf16(fa0, fb, acc[0][ct], 0, 0, 0);
                acc[1][ct] = __builtin_amdgcn_mfma_f32_16x16x32_bf16(fa1, fb, acc[1][ct], 0, 0, 0);
            }
        }
        for (int kc = 0; kc < 3; ++kc) {            // seg3: geoF (LDS)
            int col = kc * 32 + ko;
            short8 fa0 = *(const short8*)&geoF[l16 * GFW + col];
            short8 fa1 = *(const short8*)&geoF[(16 + l16) * GFW + col];
            for (int ct = 0; ct < 8; ++ct) {
                short8 fb = *(const short8*)(W1T + (ct * 16 + l16) * 608 + 512 + col);
                acc[0][ct] = __builtin_amdgcn_mfma_f32_16x16x32_bf16(fa0, fb, acc[0][ct], 0, 0, 0);
                acc[1][ct] = __builtin_amdgcn_mfma_f32_16x16x32_bf16(fa1, fb, acc[1][ct], 0, 0, 0);
            }
        }
        for (int ct = 0; ct < 8; ++ct) {
            int col = ct * 16 + l16;
            float bb = b1g[col];
            for (int rt = 0; rt < 2; ++rt)
                for (int r = 0; r < 4; ++r) {
                    int row = rt * 16 + quad * 4 + r;
                    buf1[row * BUFW + col] = f2b(gelu_f(acc[rt][ct][r] + bb));
                }
        }
    }

    // ---- stage 2: buf1 @ W2T -> gelu -> buf1 (read-all-then-write, wave-safe) ----
    {
        short8 Af[2][4];
        for (int kc = 0; kc < 4; ++kc) {
            Af[0][kc] = *(const short8*)&buf1[l16 * BUFW + kc * 32 + ko];
            Af[1][kc] = *(const short8*)&buf1[(16 + l16) * BUFW + kc * 32 + ko];
        }
        floatx4 acc[2][8];
        for (int rt = 0; rt < 2; ++rt) for (int ct = 0; ct < 8; ++ct) acc[rt][ct] = (floatx4){0,0,0,0};
        for (int kc = 0; kc < 4; ++kc)
            for (int ct = 0; ct < 8; ++ct) {
                short8 fb = *(const short8*)(W2T + (ct * 16 + l16) * 128 + kc * 32 + ko);
                acc[0][ct] = __builtin_amdgcn_mfma_f32_16x16x32_bf16(Af[0][kc], fb, acc[0][ct], 0, 0, 0);
                acc[1][ct] = __builtin_amdgcn_mfma_f32_16x16x32_bf16(Af[1][kc], fb, acc[1][ct], 0, 0, 0);
            }
        for (int ct = 0; ct < 8; ++ct) {
            int col = ct * 16 + l16;
            float bb = b2g[col];
            for (int rt = 0; rt < 2; ++rt)
                for (int r = 0; r < 4; ++r) {
                    int row = rt * 16 + quad * 4 + r;
                    buf1[row * BUFW + col] = f2b(gelu_f(acc[rt][ct][r] + bb));
                }
        }
    }

    // ---- stage 3: buf1 @ W3T + b3 -> masked mean over k -> F_nm ----
    {
        short8 Af[2][4];
        for (int kc = 0; kc < 4; ++kc) {
            Af[0][kc] = *(const short8*)&buf1[l16 * BUFW + kc * 32 + ko];
            Af[1][kc] = *(const short8*)&buf1[(16 + l16) * BUFW + kc * 32 + ko];
        }
        floatx4 acc[2][8];
        for (int rt = 0; rt < 2; ++rt) for (int ct = 0; ct < 8; ++ct) acc[rt][ct] = (floatx4){0,0,0,0};
        for (int kc = 0; kc < 4; ++kc)
            for (int ct = 0; ct < 8; ++ct) {
                short8 fb = *(const short8*)(W3T + (ct * 16 + l16) * 128 + kc * 32 + ko);
                acc[0][ct] = __builtin_amdgcn_mfma_f32_16x16x32_bf16(Af[0][kc], fb, acc[0][ct], 0, 0, 0);
                acc[1][ct] = __builtin_amdgcn_mfma_f32_16x16x32_bf16(Af[1][kc], fb, acc[1][ct], 0, 0, 0);
            }
        for (int ct = 0; ct < 8; ++ct) {
            int col = ct * 16 + l16;
            float bb = b3g[col];
            float cs = 0.0f;
            for (int rt = 0; rt < 2; ++rt)
                for (int r = 0; r < 4; ++r)
                    cs += (acc[rt][ct][r] + bb) * maskR[rt][r];
            cs += __shfl_xor(cs, 16, 64);
            cs += __shfl_xor(cs, 32, 64);
            if (lane < 16) F[640 + col] = cs;       // writes after all buf1 reads done
        }
    }

    // ---- tail (per wave): LN1 -> FFN -> LN2 -> out ----
    {
        int c0 = lane, c1 = lane + 64;
        float xb0 = hVb[c0] + F[640 + c0];
        float xb1 = hVb[c1] + F[640 + c1];
        float s = xb0 + xb1, q = xb0 * xb0 + xb1 * xb1;
        for (int o = 32; o; o >>= 1) { s += __shfl_xor(s, o, 64); q += __shfl_xor(q, o, 64); }
        float m = s * (1.0f / 128.0f);
        float inv = 1.0f / sqrtf(q * (1.0f / 128.0f) - m * m + 1e-5f);
        float h0 = (xb0 - m) * inv * g1[c0] + be1[c0];
        float h1 = (xb1 - m) * inv * g1[c1] + be1[c1];
        F[c0] = h0; F[c1] = h1;

        // FFN1: 8 outputs per lane (o = lane + 64j), coalesced-ish WiT rows
        for (int j = 0; j < 8; ++j) {
            int o = lane + 64 * j;
            const ushort8* wr = (const ushort8*)(WiT + o * 128);
            float sacc = big[o];
            for (int c8 = 0; c8 < 16; ++c8) {
                ushort8 v = wr[c8];
                const float* hp = &F[c8 * 8];
                sacc += hp[0] * b2f(v[0]) + hp[1] * b2f(v[1]) + hp[2] * b2f(v[2]) + hp[3] * b2f(v[3]) +
                        hp[4] * b2f(v[4]) + hp[5] * b2f(v[5]) + hp[6] * b2f(v[6]) + hp[7] * b2f(v[7]);
            }
            F[128 + o] = gelu_f(sacc);
        }

        // FFN2: 2 outputs per lane over gS[512]
        float d0 = bog[c0], d1 = bog[c1];
        {
            const ushort8* w0 = (const ushort8*)(WoT + c0 * 512);
            const ushort8* w1 = (const ushort8*)(WoT + c1 * 512);
            for (int o8 = 0; o8 < 64; ++o8) {
                ushort8 v0 = w0[o8], v1 = w1[o8];
                const float* gp = &F[128 + o8 * 8];
                d0 += gp[0] * b2f(v0[0]) + gp[1] * b2f(v0[1]) + gp[2] * b2f(v0[2]) + gp[3] * b2f(v0[3]) +
                      gp[4] * b2f(v0[4]) + gp[5] * b2f(v0[5]) + gp[6] * b2f(v0[6]) + gp[7] * b2f(v0[7]);
                d1 += gp[0] * b2f(v1[0]) + gp[1] * b2f(v1[1]) + gp[2] * b2f(v1[2]) + gp[3] * b2f(v1[3]) +
                      gp[4] * b2f(v1[4]) + gp[5] * b2f(v1[5]) + gp[6] * b2f(v1[6]) + gp[7] * b2f(v1[7]);
            }
        }
        float y0 = h0 + d0, y1 = h1 + d1;
        float s2 = y0 + y1, q2 = y0 * y0 + y1 * y1;
        for (int o = 32; o; o >>= 1) { s2 += __shfl_xor(s2, o, 64); q2 += __shfl_xor(q2, o, 64); }
        float m2 = s2 * (1.0f / 128.0f);
        float inv2 = 1.0f / sqrtf(q2 * (1.0f / 128.0f) - m2 * m2 + 1e-5f);
        float mv = mask_V[site];
        out[site * 128 + c0] = ((y0 - m2) * inv2 * g2[c0] + be2[c0]) * mv;
        out[site * 128 + c1] = ((y1 - m2) * inv2 * g2[c1] + be2[c1]) * mv;
    }
}

extern "C" void kernel_launch(void* const* d_in, const int* in_sizes, int n_in,
                              void* d_out, int out_size, void* d_ws, size_t ws_size,
                              hipStream_t stream) {
    const float* h_V = (const float*)d_in[0];
    const float* h_E = (const float*)d_in[1];
    // d_in[2] = E_idx (int32, unused by reference)
    const float* Xn  = (const float*)d_in[3];
    const float* mV  = (const float*)d_in[4];
    const float* mA  = (const float*)d_in[5];
    const float* Wp  = (const float*)d_in[6];
    const float* bp  = (const float*)d_in[7];
    const float* W1  = (const float*)d_in[8];
    const float* b1  = (const float*)d_in[9];
    const float* W2  = (const float*)d_in[10];
    const float* b2  = (const float*)d_in[11];
    const float* W3  = (const float*)d_in[12];
    const float* b3  = (const float*)d_in[13];
    const float* Wi  = (const float*)d_in[14];
    const float* bi  = (const float*)d_in[15];
    const float* Wo  = (const float*)d_in[16];
    const float* bo  = (const float*)d_in[17];
    const float* g1  = (const float*)d_in[18];
    const float* be1 = (const float*)d_in[19];
    const float* g2  = (const float*)d_in[20];
    const float* be2 = (const float*)d_in[21];
    unsigned short* ws = (unsigned short*)d_ws;
    float* out = (float*)d_out;

    prep_kernel<<<960, 256, 0, stream>>>(W1, W2, W3, Wi, Wo, Wp, ws);
    main_kernel<<<(B_ * L_) / 2, 128, 0, stream>>>(h_V, h_E, Xn, mV, mA, bp,
                                                   b1, b2, b3, bi, bo,
                                                   g1, be1, g2, be2, ws, out);
}

// Round 6
// 541.498 us; speedup vs baseline: 1.3986x; 1.0455x over previous
//
#include <hip/hip_runtime.h>

#define B_ 8
#define L_ 512
#define K_ 30
#define NIN_ 384
#define HES 11520          // floats per site in h_E
#define BUFW 136           // buf1 row stride (ushort)
#define GFW 96             // geoF row stride (ushort)
#define PWU 4608           // ushorts per wave arena (9216 B)
// f32 indices inside wave arena:
#define R0_OFF 0
#define T0_OFF 9
#define PL0_OFF 12
#define NPG_OFF 40         // Npg[30][24] -> 40..759  (bytes 160..3040)
#define PLF_OFF 760        // Pl[30][24]  -> 760..1479 (bytes 3040..5920, dies before geoF)
#define NM_OFF 640
// ushort index of geoF base (byte 3040, overlays dead PlFull):
#define GEOF_OFF 1520

typedef __attribute__((ext_vector_type(8))) short short8;
typedef __attribute__((ext_vector_type(8))) unsigned short ushort8;
typedef __attribute__((ext_vector_type(4))) float floatx4;
typedef __attribute__((ext_vector_type(4))) float f32x4;

__device__ __forceinline__ float b2f(unsigned short u) {
    union { unsigned int i; float f; } x; x.i = ((unsigned int)u) << 16; return x.f;
}
__device__ __forceinline__ unsigned short f2b(float f) {
    unsigned int u = __builtin_bit_cast(unsigned int, f);
    return (unsigned short)((u + 0x7fffu + ((u >> 16) & 1u)) >> 16);
}
__device__ __forceinline__ float gelu_f(float x) {
    return 0.5f * x * (1.0f + erff(x * 0.70710678118654752440f));
}
__device__ __forceinline__ short8 pack8(const float* p) {
    f32x4 lo = *(const f32x4*)p;
    f32x4 hi = *(const f32x4*)(p + 4);
    short8 r;
    r[0] = (short)f2b(lo[0]); r[1] = (short)f2b(lo[1]);
    r[2] = (short)f2b(lo[2]); r[3] = (short)f2b(lo[3]);
    r[4] = (short)f2b(hi[0]); r[5] = (short)f2b(hi[1]);
    r[6] = (short)f2b(hi[2]); r[7] = (short)f2b(hi[3]);
    return r;
}

// ws layout (ushort, bf16): W1T[128][608]@0, W2T[128][128]@77824, W3T[128][128]@94208,
// WiT[512][128]@110592, WoT[128][512]@176128, WpT[32][128]@241664. total 245760.
// LDS-tiled transpose: coalesced f32 reads, conflict-free LDS, coalesced ushort8 writes.
__global__ __launch_bounds__(256) void prep_kernel(
        const float* __restrict__ W1, const float* __restrict__ W2,
        const float* __restrict__ W3, const float* __restrict__ Wi,
        const float* __restrict__ Wo, const float* __restrict__ Wp,
        unsigned short* __restrict__ ws) {
    __shared__ float T[64][65];
    int b = blockIdx.x, tid = threadIdx.x;
    const float* in; int K, N, NOUT, KP; size_t off; int kt, nt;
    if (b < 20)      { in = W1; K = 584; N = 128; NOUT = 128; KP = 608; off = 0;      kt = b / 2; nt = b % 2; }
    else if (b < 24) { b -= 20; in = W2; K = 128; N = 128; NOUT = 128; KP = 128; off = 77824;  kt = b / 2; nt = b % 2; }
    else if (b < 28) { b -= 24; in = W3; K = 128; N = 128; NOUT = 128; KP = 128; off = 94208;  kt = b / 2; nt = b % 2; }
    else if (b < 44) { b -= 28; in = Wi; K = 128; N = 512; NOUT = 512; KP = 128; off = 110592; kt = b / 8; nt = b % 8; }
    else if (b < 60) { b -= 44; in = Wo; K = 512; N = 128; NOUT = 128; KP = 512; off = 176128; kt = b % 8; nt = b / 8; }
    else             { b -= 60; in = Wp; K = 128; N = 24;  NOUT = 32;  KP = 128; off = 241664; kt = b;     nt = 0; }

    for (int t = 0; t < 16; ++t) {
        int idx = t * 256 + tid;
        int r = idx >> 6, c = idx & 63;
        int gk = kt * 64 + r, gn = nt * 64 + c;
        T[c][r] = (gk < K && gn < N) ? in[(size_t)gk * N + gn] : 0.0f;
    }
    __syncthreads();
    for (int t = 0; t < 2; ++t) {
        int j = t * 256 + tid;
        int orow = j >> 3, oseg = (j & 7) * 8;
        int gn = nt * 64 + orow, gk = kt * 64 + oseg;
        if (gn < NOUT && gk < KP) {
            ushort8 o8;
            for (int i = 0; i < 8; ++i) o8[i] = f2b(T[orow][oseg + i]);
            *(ushort8*)(ws + off + (size_t)gn * KP + gk) = o8;
        }
    }
}

// One wave per (b,l) site, zero __syncthreads. Per-wave 9216-B LDS arena with
// strictly ordered lifetimes (same-wave LDS pipe is in-order):
//   geo phase:   R0/T0/Pl0 @0..160B, Npg @160..3040B, PlFull @3040..5920B
//   features:    geoF(bf16) @3040..8800B (PlFull dead)
//   stages 1-3:  buf1(bf16 32x136) @0..8704B (geo dead after seg3 reads)
//   tail:        F f32 hS@0 gS@128 nm@640 (buf1 dead after Af reads)
__global__ __launch_bounds__(128, 4) void main_kernel(
    const float* __restrict__ h_V,
    const float* __restrict__ h_E,
    const float* __restrict__ Xn,
    const float* __restrict__ mask_V,
    const float* __restrict__ mask_attend,
    const float* __restrict__ bp,
    const float* __restrict__ b1g,
    const float* __restrict__ b2g,
    const float* __restrict__ b3g,
    const float* __restrict__ big,
    const float* __restrict__ bog,
    const float* __restrict__ g1,
    const float* __restrict__ be1,
    const float* __restrict__ g2,
    const float* __restrict__ be2,
    const unsigned short* __restrict__ wsT,
    float* __restrict__ out) {

    __shared__ __align__(16) unsigned short lds[2 * PWU];

    const int tid  = threadIdx.x;
    const int wv   = tid >> 6;
    const int lane = tid & 63;
    const int quad = lane >> 4;
    const int l16  = lane & 15;
    const int ko   = quad * 8;
    const int site = blockIdx.x * 2 + wv;

    unsigned short* wl   = lds + wv * PWU;
    unsigned short* buf1 = wl;
    unsigned short* geoF = wl + GEOF_OFF;
    float*          Fv   = (float*)wl;

    const unsigned short* W1T = wsT;
    const unsigned short* W2T = wsT + 77824;
    const unsigned short* W3T = wsT + 94208;
    const unsigned short* WiT = wsT + 110592;
    const unsigned short* WoT = wsT + 176128;
    const unsigned short* WpT = wsT + 241664;

    const float* hEb = h_E + (size_t)site * HES;
    const float* hVb = h_V + site * 128;
    const short8 z8 = {0, 0, 0, 0, 0, 0, 0, 0};

    float maskR[2][4];
    for (int rt = 0; rt < 2; ++rt)
        for (int r = 0; r < 4; ++r) {
            int row = rt * 16 + quad * 4 + r;
            maskR[rt][r] = (row < K_) ? mask_attend[site * K_ + row] * (1.0f / 30.0f) : 0.0f;
        }

    // ---- frames in REGISTERS (lanes 0..29): R[i][j]=e_j[i] ----
    float Rr[9], Tt[3];
    if (lane < K_) {
        const float* xp = Xn + ((size_t)site * K_ + lane) * 9;
        float Nx = xp[0], Ny = xp[1], Nz = xp[2];
        float Ax = xp[3], Ay = xp[4], Az = xp[5];
        float Cx = xp[6], Cy = xp[7], Cz = xp[8];
        float e0x = Ax - Nx, e0y = Ay - Ny, e0z = Az - Nz;
        float r0 = 1.0f / sqrtf(e0x * e0x + e0y * e0y + e0z * e0z + 1e-8f);
        e0x *= r0; e0y *= r0; e0z *= r0;
        float u1x = Cx - Ax, u1y = Cy - Ay, u1z = Cz - Az;
        float d = e0x * u1x + e0y * u1y + e0z * u1z;
        u1x -= e0x * d; u1y -= e0y * d; u1z -= e0z * d;
        float r1 = 1.0f / sqrtf(u1x * u1x + u1y * u1y + u1z * u1z + 1e-8f);
        u1x *= r1; u1y *= r1; u1z *= r1;
        Rr[0] = e0x; Rr[1] = u1x; Rr[2] = e0y * u1z - e0z * u1y;
        Rr[3] = e0y; Rr[4] = u1y; Rr[5] = e0z * u1x - e0x * u1z;
        Rr[6] = e0z; Rr[7] = u1z; Rr[8] = e0x * u1y - e0y * u1x;
        Tt[0] = Ax; Tt[1] = Ay; Tt[2] = Az;
    }

    // ---- p_ln MFMA -> PlFull LDS ----
    {
        floatx4 a[2][2] = {{{0,0,0,0},{0,0,0,0}},{{0,0,0,0},{0,0,0,0}}};
        for (int kc = 0; kc < 4; ++kc) {
            int col = 256 + kc * 32 + ko;
            short8 fa0 = pack8(hEb + l16 * NIN_ + col);
            int r1 = 16 + l16;
            short8 fa1 = (r1 < K_) ? pack8(hEb + r1 * NIN_ + col) : z8;
            for (int ct = 0; ct < 2; ++ct) {
                short8 fb = *(const short8*)(WpT + (ct * 16 + l16) * 128 + kc * 32 + ko);
                a[0][ct] = __builtin_amdgcn_mfma_f32_16x16x32_bf16(fa0, fb, a[0][ct], 0, 0, 0);
                a[1][ct] = __builtin_amdgcn_mfma_f32_16x16x32_bf16(fa1, fb, a[1][ct], 0, 0, 0);
            }
        }
        for (int ct = 0; ct < 2; ++ct) {
            int ccol = ct * 16 + l16;
            if (ccol < 24) {
                float bpc = bp[ccol];
                for (int rt = 0; rt < 2; ++rt)
                    for (int i = 0; i < 4; ++i) {
                        int row = rt * 16 + quad * 4 + i;
                        if (row < K_) Fv[PLF_OFF + row * 24 + ccol] = a[rt][ct][i] + bpc;
                    }
            }
        }
    }

    // ---- npg by lane k (consumes PlFull; writes Npg; lane0 writes R0/T0/Pl0) ----
    if (lane < K_) {
        float pl[24];
        #pragma unroll
        for (int c = 0; c < 24; ++c) pl[c] = Fv[PLF_OFF + lane * 24 + c];
        if (lane == 0) {
            #pragma unroll
            for (int i = 0; i < 9; ++i) Fv[R0_OFF + i] = Rr[i];
            Fv[T0_OFF] = Tt[0]; Fv[T0_OFF + 1] = Tt[1]; Fv[T0_OFF + 2] = Tt[2];
            #pragma unroll
            for (int c = 0; c < 24; ++c) Fv[PL0_OFF + c] = pl[c];
        }
        #pragma unroll
        for (int n = 0; n < 8; ++n) {
            float p0 = pl[n * 3], p1 = pl[n * 3 + 1], p2 = pl[n * 3 + 2];
            #pragma unroll
            for (int i = 0; i < 3; ++i)
                Fv[NPG_OFF + lane * 24 + n * 3 + i] =
                    Rr[i * 3 + 0] * p0 + Rr[i * 3 + 1] * p1 + Rr[i * 3 + 2] * p2 + Tt[i];
        }
    }

    // ---- features -> geoF (overlays dead PlFull). cols: ple@0 pln@24 npl@32 npln@56 npgn@64, 72..95 zero ----
    for (int id = lane; id < 720; id += 64) geoF[(id / 24) * GFW + 72 + id % 24] = 0;
    {
        float R00 = Fv[0], R01 = Fv[1], R02 = Fv[2], R03 = Fv[3], R04 = Fv[4];
        float R05 = Fv[5], R06 = Fv[6], R07 = Fv[7], R08 = Fv[8];
        float T00 = Fv[9], T01 = Fv[10], T02 = Fv[11];
        for (int id = lane; id < 240; id += 64) {
            int k = id >> 3, n = id & 7;
            float p0 = Fv[PL0_OFF + n * 3], p1 = Fv[PL0_OFF + n * 3 + 1], p2 = Fv[PL0_OFF + n * 3 + 2];
            float q0g = Fv[NPG_OFF + n * 3], q1g = Fv[NPG_OFF + n * 3 + 1], q2g = Fv[NPG_OFF + n * 3 + 2];
            float a0 = Fv[NPG_OFF + k * 24 + n * 3];
            float a1 = Fv[NPG_OFF + k * 24 + n * 3 + 1];
            float a2 = Fv[NPG_OFF + k * 24 + n * 3 + 2];
            float d0 = a0 - T00, d1 = a1 - T01, d2 = a2 - T02;
            float nl0 = R00 * d0 + R03 * d1 + R06 * d2;
            float nl1 = R01 * d0 + R04 * d1 + R07 * d2;
            float nl2 = R02 * d0 + R05 * d1 + R08 * d2;
            unsigned short* gf = geoF + k * GFW;
            gf[0 + n * 3] = f2b(p0); gf[1 + n * 3] = f2b(p1); gf[2 + n * 3] = f2b(p2);
            gf[24 + n] = f2b(sqrtf(p0 * p0 + p1 * p1 + p2 * p2 + 1e-8f));
            gf[32 + n * 3] = f2b(nl0); gf[33 + n * 3] = f2b(nl1); gf[34 + n * 3] = f2b(nl2);
            gf[56 + n] = f2b(sqrtf(nl0 * nl0 + nl1 * nl1 + nl2 * nl2 + 1e-8f));
            float q0 = q0g - a0, q1 = q1g - a1, q2 = q2g - a2;
            gf[64 + n] = f2b(sqrtf(q0 * q0 + q1 * q1 + q2 * q2 + 1e-8f));
        }
    }

    // ---- stage 1: [32 x 608] @ W1T -> gelu -> buf1 ----
    {
        floatx4 acc[2][8];
        for (int rt = 0; rt < 2; ++rt) for (int ct = 0; ct < 8; ++ct) acc[rt][ct] = (floatx4){0,0,0,0};
        for (int kc = 0; kc < 4; ++kc) {            // seg1: h_V (rows identical)
            int col = kc * 32 + ko;
            short8 fa = pack8(hVb + col);
            for (int ct = 0; ct < 8; ++ct) {
                short8 fb = *(const short8*)(W1T + (ct * 16 + l16) * 608 + col);
                acc[0][ct] = __builtin_amdgcn_mfma_f32_16x16x32_bf16(fa, fb, acc[0][ct], 0, 0, 0);
                acc[1][ct] = __builtin_amdgcn_mfma_f32_16x16x32_bf16(fa, fb, acc[1][ct], 0, 0, 0);
            }
        }
        for (int kc = 0; kc < 12; ++kc) {           // seg2: h_E
            int col = kc * 32 + ko;
            short8 fa0 = pack8(hEb + l16 * NIN_ + col);
            int r1 = 16 + l16;
            short8 fa1 = (r1 < K_) ? pack8(hEb + r1 * NIN_ + col) : z8;
            for (int ct = 0; ct < 8; ++ct) {
                short8 fb = *(const short8*)(W1T + (ct * 16 + l16) * 608 + 128 + col);
                acc[0][ct] = __builtin_amdgcn_mfma_f32_16x16x32_bf16(fa0, fb, acc[0][ct], 0, 0, 0);
                acc[1][ct] = __builtin_amdgcn_mfma_f32_16x16x32_bf16(fa1, fb, acc[1][ct], 0, 0, 0);
            }
        }
        for (int kc = 0; kc < 3; ++kc) {            // seg3: geoF (LDS), rows 30/31 -> zero frags
            int col = kc * 32 + ko;
            short8 fa0 = *(const short8*)&geoF[l16 * GFW + col];
            int r1 = 16 + l16;
            short8 fa1 = (r1 < K_) ? *(const short8*)&geoF[r1 * GFW + col] : z8;
            for (int ct = 0; ct < 8; ++ct) {
                short8 fb = *(const short8*)(W1T + (ct * 16 + l16) * 608 + 512 + col);
                acc[0][ct] = __builtin_amdgcn_mfma_f32_16x16x32_bf16(fa0, fb, acc[0][ct], 0, 0, 0);
                acc[1][ct] = __builtin_amdgcn_mfma_f32_16x16x32_bf16(fa1, fb, acc[1][ct], 0, 0, 0);
            }
        }
        for (int ct = 0; ct < 8; ++ct) {            // epilogue (after all geoF reads)
            int col = ct * 16 + l16;
            float bb = b1g[col];
            for (int rt = 0; rt < 2; ++rt)
                for (int r = 0; r < 4; ++r) {
                    int row = rt * 16 + quad * 4 + r;
                    buf1[row * BUFW + col] = f2b(gelu_f(acc[rt][ct][r] + bb));
                }
        }
    }

    // ---- stage 2: buf1 @ W2T -> gelu -> buf1 ----
    {
        short8 Af[2][4];
        for (int kc = 0; kc < 4; ++kc) {
            Af[0][kc] = *(const short8*)&buf1[l16 * BUFW + kc * 32 + ko];
            Af[1][kc] = *(const short8*)&buf1[(16 + l16) * BUFW + kc * 32 + ko];
        }
        floatx4 acc[2][8];
        for (int rt = 0; rt < 2; ++rt) for (int ct = 0; ct < 8; ++ct) acc[rt][ct] = (floatx4){0,0,0,0};
        for (int kc = 0; kc < 4; ++kc)
            for (int ct = 0; ct < 8; ++ct) {
                short8 fb = *(const short8*)(W2T + (ct * 16 + l16) * 128 + kc * 32 + ko);
                acc[0][ct] = __builtin_amdgcn_mfma_f32_16x16x32_bf16(Af[0][kc], fb, acc[0][ct], 0, 0, 0);
                acc[1][ct] = __builtin_amdgcn_mfma_f32_16x16x32_bf16(Af[1][kc], fb, acc[1][ct], 0, 0, 0);
            }
        for (int ct = 0; ct < 8; ++ct) {
            int col = ct * 16 + l16;
            float bb = b2g[col];
            for (int rt = 0; rt < 2; ++rt)
                for (int r = 0; r < 4; ++r) {
                    int row = rt * 16 + quad * 4 + r;
                    buf1[row * BUFW + col] = f2b(gelu_f(acc[rt][ct][r] + bb));
                }
        }
    }

    // ---- stage 3: buf1 @ W3T + b3 -> masked mean -> nm ----
    {
        short8 Af[2][4];
        for (int kc = 0; kc < 4; ++kc) {
            Af[0][kc] = *(const short8*)&buf1[l16 * BUFW + kc * 32 + ko];
            Af[1][kc] = *(const short8*)&buf1[(16 + l16) * BUFW + kc * 32 + ko];
        }
        floatx4 acc[2][8];
        for (int rt = 0; rt < 2; ++rt) for (int ct = 0; ct < 8; ++ct) acc[rt][ct] = (floatx4){0,0,0,0};
        for (int kc = 0; kc < 4; ++kc)
            for (int ct = 0; ct < 8; ++ct) {
                short8 fb = *(const short8*)(W3T + (ct * 16 + l16) * 128 + kc * 32 + ko);
                acc[0][ct] = __builtin_amdgcn_mfma_f32_16x16x32_bf16(Af[0][kc], fb, acc[0][ct], 0, 0, 0);
                acc[1][ct] = __builtin_amdgcn_mfma_f32_16x16x32_bf16(Af[1][kc], fb, acc[1][ct], 0, 0, 0);
            }
        for (int ct = 0; ct < 8; ++ct) {
            int col = ct * 16 + l16;
            float bb = b3g[col];
            float cs = 0.0f;
            for (int rt = 0; rt < 2; ++rt)
                for (int r = 0; r < 4; ++r)
                    cs += (acc[rt][ct][r] + bb) * maskR[rt][r];
            cs += __shfl_xor(cs, 16, 64);
            cs += __shfl_xor(cs, 32, 64);
            if (lane < 16) Fv[NM_OFF + col] = cs;
        }
    }

    // ---- tail: LN1 -> FFN -> LN2 -> out ----
    {
        int c0 = lane, c1 = lane + 64;
        float xb0 = hVb[c0] + Fv[NM_OFF + c0];
        float xb1 = hVb[c1] + Fv[NM_OFF + c1];
        float s = xb0 + xb1, q = xb0 * xb0 + xb1 * xb1;
        for (int o = 32; o; o >>= 1) { s += __shfl_xor(s, o, 64); q += __shfl_xor(q, o, 64); }
        float m = s * (1.0f / 128.0f);
        float inv = 1.0f / sqrtf(q * (1.0f / 128.0f) - m * m + 1e-5f);
        float h0 = (xb0 - m) * inv * g1[c0] + be1[c0];
        float h1 = (xb1 - m) * inv * g1[c1] + be1[c1];
        Fv[c0] = h0; Fv[c1] = h1;

        for (int j = 0; j < 8; ++j) {
            int o = lane + 64 * j;
            const ushort8* wr = (const ushort8*)(WiT + o * 128);
            float sa = big[o], sb = 0.0f;
            for (int c8 = 0; c8 < 16; c8 += 2) {
                ushort8 v0 = wr[c8], v1 = wr[c8 + 1];
                const float* hp0 = &Fv[c8 * 8];
                const float* hp1 = &Fv[c8 * 8 + 8];
                sa += hp0[0] * b2f(v0[0]) + hp0[1] * b2f(v0[1]) + hp0[2] * b2f(v0[2]) + hp0[3] * b2f(v0[3]) +
                      hp0[4] * b2f(v0[4]) + hp0[5] * b2f(v0[5]) + hp0[6] * b2f(v0[6]) + hp0[7] * b2f(v0[7]);
                sb += hp1[0] * b2f(v1[0]) + hp1[1] * b2f(v1[1]) + hp1[2] * b2f(v1[2]) + hp1[3] * b2f(v1[3]) +
                      hp1[4] * b2f(v1[4]) + hp1[5] * b2f(v1[5]) + hp1[6] * b2f(v1[6]) + hp1[7] * b2f(v1[7]);
            }
            Fv[128 + o] = gelu_f(sa + sb);
        }

        float d0a = bog[c0], d0b = 0.0f, d1a = bog[c1], d1b = 0.0f;
        {
            const ushort8* w0 = (const ushort8*)(WoT + c0 * 512);
            const ushort8* w1 = (const ushort8*)(WoT + c1 * 512);
            for (int o8 = 0; o8 < 64; o8 += 2) {
                ushort8 v0 = w0[o8], v0n = w0[o8 + 1];
                ushort8 v1 = w1[o8], v1n = w1[o8 + 1];
                const float* gp = &Fv[128 + o8 * 8];
                const float* gq = gp + 8;
                d0a += gp[0] * b2f(v0[0]) + gp[1] * b2f(v0[1]) + gp[2] * b2f(v0[2]) + gp[3] * b2f(v0[3]) +
                       gp[4] * b2f(v0[4]) + gp[5] * b2f(v0[5]) + gp[6] * b2f(v0[6]) + gp[7] * b2f(v0[7]);
                d0b += gq[0] * b2f(v0n[0]) + gq[1] * b2f(v0n[1]) + gq[2] * b2f(v0n[2]) + gq[3] * b2f(v0n[3]) +
                       gq[4] * b2f(v0n[4]) + gq[5] * b2f(v0n[5]) + gq[6] * b2f(v0n[6]) + gq[7] * b2f(v0n[7]);
                d1a += gp[0] * b2f(v1[0]) + gp[1] * b2f(v1[1]) + gp[2] * b2f(v1[2]) + gp[3] * b2f(v1[3]) +
                       gp[4] * b2f(v1[4]) + gp[5] * b2f(v1[5]) + gp[6] * b2f(v1[6]) + gp[7] * b2f(v1[7]);
                d1b += gq[0] * b2f(v1n[0]) + gq[1] * b2f(v1n[1]) + gq[2] * b2f(v1n[2]) + gq[3] * b2f(v1n[3]) +
                       gq[4] * b2f(v1n[4]) + gq[5] * b2f(v1n[5]) + gq[6] * b2f(v1n[6]) + gq[7] * b2f(v1n[7]);
            }
        }
        float y0 = h0 + d0a + d0b, y1 = h1 + d1a + d1b;
        float s2 = y0 + y1, q2 = y0 * y0 + y1 * y1;
        for (int o = 32; o; o >>= 1) { s2 += __shfl_xor(s2, o, 64); q2 += __shfl_xor(q2, o, 64); }
        float m2 = s2 * (1.0f / 128.0f);
        float inv2 = 1.0f / sqrtf(q2 * (1.0f / 128.0f) - m2 * m2 + 1e-5f);
        float mv = mask_V[site];
        out[site * 128 + c0] = ((y0 - m2) * inv2 * g2[c0] + be2[c0]) * mv;
        out[site * 128 + c1] = ((y1 - m2) * inv2 * g2[c1] + be2[c1]) * mv;
    }
}

extern "C" void kernel_launch(void* const* d_in, const int* in_sizes, int n_in,
                              void* d_out, int out_size, void* d_ws, size_t ws_size,
                              hipStream_t stream) {
    const float* h_V = (const float*)d_in[0];
    const float* h_E = (const float*)d_in[1];
    // d_in[2] = E_idx (int32, unused by reference)
    const float* Xn  = (const float*)d_in[3];
    const float* mV  = (const float*)d_in[4];
    const float* mA  = (const float*)d_in[5];
    const float* Wp  = (const float*)d_in[6];
    const float* bp  = (const float*)d_in[7];
    const float* W1  = (const float*)d_in[8];
    const float* b1  = (const float*)d_in[9];
    const float* W2  = (const float*)d_in[10];
    const float* b2  = (const float*)d_in[11];
    const float* W3  = (const float*)d_in[12];
    const float* b3  = (const float*)d_in[13];
    const float* Wi  = (const float*)d_in[14];
    const float* bi  = (const float*)d_in[15];
    const float* Wo  = (const float*)d_in[16];
    const float* bo  = (const float*)d_in[17];
    const float* g1  = (const float*)d_in[18];
    const float* be1 = (const float*)d_in[19];
    const float* g2  = (const float*)d_in[20];
    const float* be2 = (const float*)d_in[21];
    unsigned short* ws = (unsigned short*)d_ws;
    float* out = (float*)d_out;

    prep_kernel<<<62, 256, 0, stream>>>(W1, W2, W3, Wi, Wo, Wp, ws);
    main_kernel<<<(B_ * L_) / 2, 128, 0, stream>>>(h_V, h_E, Xn, mV, mA, bp,
                                                   b1, b2, b3, bi, bo,
                                                   g1, be1, g2, be2, ws, out);
}

// Round 7
// 444.614 us; speedup vs baseline: 1.7034x; 1.2179x over previous
//
#include <hip/hip_runtime.h>

#define B_ 8
#define L_ 512
#define K_ 30
#define NIN_ 384
#define HES 11520          // floats per site in h_E
#define BUFW 136           // buf1 row stride (ushort)
#define GFW 96             // geoF row stride (ushort)
#define PWU 4608           // ushorts per wave arena (9216 B)
// f32 indices inside wave arena:
#define R0_OFF 0
#define T0_OFF 9
#define PL0_OFF 12
#define NPG_OFF 40         // Npg[30][24] -> 40..759
#define PLF_OFF 760        // Pl[30][24] -> 760..1479 (dies before geoF)
#define NM_OFF 640
#define GEOF_OFF 1520      // ushort index (byte 3040), overlays dead PlFull

// ws fragment-ordered weights (ushort, bf16):
// W1F@0 [8ct][19kc][512], W2F@77824 [8][4][512], W3F@94208 [8][4][512],
// WiF@110592 [16c8][512o][8], WoF@176128 [64o8][128c][8], WpF@241664 [2][4][512]
#define W1F_OFF 0
#define W2F_OFF 77824
#define W3F_OFF 94208
#define WIF_OFF 110592
#define WOF_OFF 176128
#define WPF_OFF 241664

typedef __attribute__((ext_vector_type(8))) short short8;
typedef __attribute__((ext_vector_type(8))) unsigned short ushort8;
typedef __attribute__((ext_vector_type(4))) float floatx4;
typedef __attribute__((ext_vector_type(4))) float f32x4;

__device__ __forceinline__ float b2f(unsigned short u) {
    union { unsigned int i; float f; } x; x.i = ((unsigned int)u) << 16; return x.f;
}
__device__ __forceinline__ unsigned short f2b(float f) {
    unsigned int u = __builtin_bit_cast(unsigned int, f);
    return (unsigned short)((u + 0x7fffu + ((u >> 16) & 1u)) >> 16);
}
__device__ __forceinline__ float gelu_f(float x) {
    return 0.5f * x * (1.0f + erff(x * 0.70710678118654752440f));
}
__device__ __forceinline__ short8 pack8(const float* p) {
    f32x4 lo = *(const f32x4*)p;
    f32x4 hi = *(const f32x4*)(p + 4);
    short8 r;
    r[0] = (short)f2b(lo[0]); r[1] = (short)f2b(lo[1]);
    r[2] = (short)f2b(lo[2]); r[3] = (short)f2b(lo[3]);
    r[4] = (short)f2b(hi[0]); r[5] = (short)f2b(hi[1]);
    r[6] = (short)f2b(hi[2]); r[7] = (short)f2b(hi[3]);
    return r;
}
__device__ __forceinline__ float dot8(const float* hp, ushort8 v) {
    return hp[0] * b2f(v[0]) + hp[1] * b2f(v[1]) + hp[2] * b2f(v[2]) + hp[3] * b2f(v[3]) +
           hp[4] * b2f(v[4]) + hp[5] * b2f(v[5]) + hp[6] * b2f(v[6]) + hp[7] * b2f(v[7]);
}

// One element per thread; grid covers 245760 exactly.
__global__ __launch_bounds__(256) void prep_kernel(
        const float* __restrict__ W1, const float* __restrict__ W2,
        const float* __restrict__ W3, const float* __restrict__ Wi,
        const float* __restrict__ Wo, const float* __restrict__ Wp,
        unsigned short* __restrict__ ws) {
    int idx = blockIdx.x * 256 + threadIdx.x;
    if (idx < 94208 || (idx >= 241664 && idx < 245760)) {
        // MFMA-fragment layouts: frag = ct*KC + kc; within frag lane*8+j;
        // lane=(quad*16+l16); value = W[k= kc*32+quad*8+j][n= ct*16+l16]
        const float* in; int i, KC, Kreal, Nreal, Nld;
        if (idx < 77824)      { in = W1; i = idx;          KC = 19; Kreal = 584; Nreal = 128; Nld = 128; }
        else if (idx < 94208) { in = W2; i = idx - 77824;  KC = 4;  Kreal = 128; Nreal = 128; Nld = 128; }
        else                  { in = Wp; i = idx - 241664; KC = 4;  Kreal = 128; Nreal = 24;  Nld = 24;  }
        int f = i >> 9, r = i & 511;
        int ct = f / KC, kc = f % KC;
        int lane = r >> 3, j = r & 7;
        int q = lane >> 4, l = lane & 15;
        int k = kc * 32 + q * 8 + j, n = ct * 16 + l;
        ws[idx] = (k < Kreal && n < Nreal) ? f2b(in[k * Nld + n]) : (unsigned short)0;
    } else if (idx < 110592) {
        // W3 fragments
        int i = idx - 94208;
        int f = i >> 9, r = i & 511;
        int ct = f >> 2, kc = f & 3;
        int lane = r >> 3, j = r & 7;
        int q = lane >> 4, l = lane & 15;
        ws[idx] = f2b(W3[(kc * 32 + q * 8 + j) * 128 + ct * 16 + l]);
    } else if (idx < 176128) {
        // WiF [c8][o][8]: val = Wi[c8*8+ii][o]
        int i = idx - 110592;
        int c8 = i >> 12, r = i & 4095;
        int o = r >> 3, ii = r & 7;
        ws[idx] = f2b(Wi[(c8 * 8 + ii) * 512 + o]);
    } else if (idx < 241664) {
        // WoF [o8][c][8]: val = Wo[o8*8+ii][c]
        int i = idx - 176128;
        int o8 = i >> 10, r = i & 1023;
        int c = r >> 3, ii = r & 7;
        ws[idx] = f2b(Wo[(o8 * 8 + ii) * 128 + c]);
    }
}

// One wave per (b,l) site, zero __syncthreads. 9216-B per-wave LDS arena,
// lifetimes strictly ordered within the wave (in-order LDS pipe).
__global__ __launch_bounds__(128, 3) void main_kernel(
    const float* __restrict__ h_V,
    const float* __restrict__ h_E,
    const float* __restrict__ Xn,
    const float* __restrict__ mask_V,
    const float* __restrict__ mask_attend,
    const float* __restrict__ bp,
    const float* __restrict__ b1g,
    const float* __restrict__ b2g,
    const float* __restrict__ b3g,
    const float* __restrict__ big,
    const float* __restrict__ bog,
    const float* __restrict__ g1,
    const float* __restrict__ be1,
    const float* __restrict__ g2,
    const float* __restrict__ be2,
    const unsigned short* __restrict__ wsT,
    float* __restrict__ out) {

    __shared__ __align__(16) unsigned short lds[2 * PWU];

    const int tid  = threadIdx.x;
    const int wv   = tid >> 6;
    const int lane = tid & 63;
    const int quad = lane >> 4;
    const int l16  = lane & 15;
    const int ko   = quad * 8;
    const int site = blockIdx.x * 2 + wv;

    unsigned short* wl   = lds + wv * PWU;
    unsigned short* buf1 = wl;
    unsigned short* geoF = wl + GEOF_OFF;
    float*          Fv   = (float*)wl;

    const unsigned short* W1F = wsT + W1F_OFF;
    const unsigned short* W2F = wsT + W2F_OFF;
    const unsigned short* W3F = wsT + W3F_OFF;
    const unsigned short* WiF = wsT + WIF_OFF;
    const unsigned short* WoF = wsT + WOF_OFF;
    const unsigned short* WpF = wsT + WPF_OFF;

    const float* hEb = h_E + (size_t)site * HES;
    const float* hVb = h_V + site * 128;
    const short8 z8 = {0, 0, 0, 0, 0, 0, 0, 0};

    float maskR[2][4];
    for (int rt = 0; rt < 2; ++rt)
        for (int r = 0; r < 4; ++r) {
            int row = rt * 16 + quad * 4 + r;
            maskR[rt][r] = (row < K_) ? mask_attend[site * K_ + row] * (1.0f / 30.0f) : 0.0f;
        }

    // ---- frames in registers (lanes 0..29): R[i][j]=e_j[i] ----
    float Rr[9], Tt[3];
    if (lane < K_) {
        const float* xp = Xn + ((size_t)site * K_ + lane) * 9;
        float Nx = xp[0], Ny = xp[1], Nz = xp[2];
        float Ax = xp[3], Ay = xp[4], Az = xp[5];
        float Cx = xp[6], Cy = xp[7], Cz = xp[8];
        float e0x = Ax - Nx, e0y = Ay - Ny, e0z = Az - Nz;
        float r0 = 1.0f / sqrtf(e0x * e0x + e0y * e0y + e0z * e0z + 1e-8f);
        e0x *= r0; e0y *= r0; e0z *= r0;
        float u1x = Cx - Ax, u1y = Cy - Ay, u1z = Cz - Az;
        float d = e0x * u1x + e0y * u1y + e0z * u1z;
        u1x -= e0x * d; u1y -= e0y * d; u1z -= e0z * d;
        float r1 = 1.0f / sqrtf(u1x * u1x + u1y * u1y + u1z * u1z + 1e-8f);
        u1x *= r1; u1y *= r1; u1z *= r1;
        Rr[0] = e0x; Rr[1] = u1x; Rr[2] = e0y * u1z - e0z * u1y;
        Rr[3] = e0y; Rr[4] = u1y; Rr[5] = e0z * u1x - e0x * u1z;
        Rr[6] = e0z; Rr[7] = u1z; Rr[8] = e0x * u1y - e0y * u1x;
        Tt[0] = Ax; Tt[1] = Ay; Tt[2] = Az;
    }

    // ---- p_ln MFMA -> PlFull LDS ----
    {
        floatx4 a[2][2] = {{{0,0,0,0},{0,0,0,0}},{{0,0,0,0},{0,0,0,0}}};
        for (int kc = 0; kc < 4; ++kc) {
            int col = 256 + kc * 32 + ko;
            short8 fa0 = pack8(hEb + l16 * NIN_ + col);
            int r1 = 16 + l16;
            short8 fa1 = (r1 < K_) ? pack8(hEb + r1 * NIN_ + col) : z8;
            for (int ct = 0; ct < 2; ++ct) {
                short8 fb = *(const short8*)(WpF + (ct * 4 + kc) * 512 + lane * 8);
                a[0][ct] = __builtin_amdgcn_mfma_f32_16x16x32_bf16(fa0, fb, a[0][ct], 0, 0, 0);
                a[1][ct] = __builtin_amdgcn_mfma_f32_16x16x32_bf16(fa1, fb, a[1][ct], 0, 0, 0);
            }
        }
        for (int ct = 0; ct < 2; ++ct) {
            int ccol = ct * 16 + l16;
            if (ccol < 24) {
                float bpc = bp[ccol];
                for (int rt = 0; rt < 2; ++rt)
                    for (int i = 0; i < 4; ++i) {
                        int row = rt * 16 + quad * 4 + i;
                        if (row < K_) Fv[PLF_OFF + row * 24 + ccol] = a[rt][ct][i] + bpc;
                    }
            }
        }
    }

    // ---- npg by lane k ----
    if (lane < K_) {
        float pl[24];
        #pragma unroll
        for (int c = 0; c < 24; ++c) pl[c] = Fv[PLF_OFF + lane * 24 + c];
        if (lane == 0) {
            #pragma unroll
            for (int i = 0; i < 9; ++i) Fv[R0_OFF + i] = Rr[i];
            Fv[T0_OFF] = Tt[0]; Fv[T0_OFF + 1] = Tt[1]; Fv[T0_OFF + 2] = Tt[2];
            #pragma unroll
            for (int c = 0; c < 24; ++c) Fv[PL0_OFF + c] = pl[c];
        }
        #pragma unroll
        for (int n = 0; n < 8; ++n) {
            float p0 = pl[n * 3], p1 = pl[n * 3 + 1], p2 = pl[n * 3 + 2];
            #pragma unroll
            for (int i = 0; i < 3; ++i)
                Fv[NPG_OFF + lane * 24 + n * 3 + i] =
                    Rr[i * 3 + 0] * p0 + Rr[i * 3 + 1] * p1 + Rr[i * 3 + 2] * p2 + Tt[i];
        }
    }

    // ---- features -> geoF (overlays dead PlFull) ----
    for (int id = lane; id < 720; id += 64) geoF[(id / 24) * GFW + 72 + id % 24] = 0;
    {
        float R00 = Fv[0], R01 = Fv[1], R02 = Fv[2], R03 = Fv[3], R04 = Fv[4];
        float R05 = Fv[5], R06 = Fv[6], R07 = Fv[7], R08 = Fv[8];
        float T00 = Fv[9], T01 = Fv[10], T02 = Fv[11];
        for (int id = lane; id < 240; id += 64) {
            int k = id >> 3, n = id & 7;
            float p0 = Fv[PL0_OFF + n * 3], p1 = Fv[PL0_OFF + n * 3 + 1], p2 = Fv[PL0_OFF + n * 3 + 2];
            float q0g = Fv[NPG_OFF + n * 3], q1g = Fv[NPG_OFF + n * 3 + 1], q2g = Fv[NPG_OFF + n * 3 + 2];
            float a0 = Fv[NPG_OFF + k * 24 + n * 3];
            float a1 = Fv[NPG_OFF + k * 24 + n * 3 + 1];
            float a2 = Fv[NPG_OFF + k * 24 + n * 3 + 2];
            float d0 = a0 - T00, d1 = a1 - T01, d2 = a2 - T02;
            float nl0 = R00 * d0 + R03 * d1 + R06 * d2;
            float nl1 = R01 * d0 + R04 * d1 + R07 * d2;
            float nl2 = R02 * d0 + R05 * d1 + R08 * d2;
            unsigned short* gf = geoF + k * GFW;
            gf[0 + n * 3] = f2b(p0); gf[1 + n * 3] = f2b(p1); gf[2 + n * 3] = f2b(p2);
            gf[24 + n] = f2b(sqrtf(p0 * p0 + p1 * p1 + p2 * p2 + 1e-8f));
            gf[32 + n * 3] = f2b(nl0); gf[33 + n * 3] = f2b(nl1); gf[34 + n * 3] = f2b(nl2);
            gf[56 + n] = f2b(sqrtf(nl0 * nl0 + nl1 * nl1 + nl2 * nl2 + 1e-8f));
            float q0 = q0g - a0, q1 = q1g - a1, q2 = q2g - a2;
            gf[64 + n] = f2b(sqrtf(q0 * q0 + q1 * q1 + q2 * q2 + 1e-8f));
        }
    }

    // ---- stage 1: [32 x 608] @ W1 -> gelu -> buf1 (coalesced fragment weights) ----
    {
        floatx4 acc[2][8];
        for (int rt = 0; rt < 2; ++rt) for (int ct = 0; ct < 8; ++ct) acc[rt][ct] = (floatx4){0,0,0,0};
        for (int kc = 0; kc < 4; ++kc) {            // kcg 0..3: h_V (rows identical)
            int col = kc * 32 + ko;
            short8 fa = pack8(hVb + col);
            for (int ct = 0; ct < 8; ++ct) {
                short8 fb = *(const short8*)(W1F + (ct * 19 + kc) * 512 + lane * 8);
                acc[0][ct] = __builtin_amdgcn_mfma_f32_16x16x32_bf16(fa, fb, acc[0][ct], 0, 0, 0);
                acc[1][ct] = __builtin_amdgcn_mfma_f32_16x16x32_bf16(fa, fb, acc[1][ct], 0, 0, 0);
            }
        }
        for (int kc = 0; kc < 12; ++kc) {           // kcg 4..15: h_E
            int col = kc * 32 + ko;
            short8 fa0 = pack8(hEb + l16 * NIN_ + col);
            int r1 = 16 + l16;
            short8 fa1 = (r1 < K_) ? pack8(hEb + r1 * NIN_ + col) : z8;
            for (int ct = 0; ct < 8; ++ct) {
                short8 fb = *(const short8*)(W1F + (ct * 19 + 4 + kc) * 512 + lane * 8);
                acc[0][ct] = __builtin_amdgcn_mfma_f32_16x16x32_bf16(fa0, fb, acc[0][ct], 0, 0, 0);
                acc[1][ct] = __builtin_amdgcn_mfma_f32_16x16x32_bf16(fa1, fb, acc[1][ct], 0, 0, 0);
            }
        }
        for (int kc = 0; kc < 3; ++kc) {            // kcg 16..18: geoF (LDS)
            int col = kc * 32 + ko;
            short8 fa0 = *(const short8*)&geoF[l16 * GFW + col];
            int r1 = 16 + l16;
            short8 fa1 = (r1 < K_) ? *(const short8*)&geoF[r1 * GFW + col] : z8;
            for (int ct = 0; ct < 8; ++ct) {
                short8 fb = *(const short8*)(W1F + (ct * 19 + 16 + kc) * 512 + lane * 8);
                acc[0][ct] = __builtin_amdgcn_mfma_f32_16x16x32_bf16(fa0, fb, acc[0][ct], 0, 0, 0);
                acc[1][ct] = __builtin_amdgcn_mfma_f32_16x16x32_bf16(fa1, fb, acc[1][ct], 0, 0, 0);
            }
        }
        for (int ct = 0; ct < 8; ++ct) {
            int col = ct * 16 + l16;
            float bb = b1g[col];
            for (int rt = 0; rt < 2; ++rt)
                for (int r = 0; r < 4; ++r) {
                    int row = rt * 16 + quad * 4 + r;
                    buf1[row * BUFW + col] = f2b(gelu_f(acc[rt][ct][r] + bb));
                }
        }
    }

    // ---- stage 2: buf1 @ W2 -> gelu -> buf1 ----
    {
        short8 Af[2][4];
        for (int kc = 0; kc < 4; ++kc) {
            Af[0][kc] = *(const short8*)&buf1[l16 * BUFW + kc * 32 + ko];
            Af[1][kc] = *(const short8*)&buf1[(16 + l16) * BUFW + kc * 32 + ko];
        }
        floatx4 acc[2][8];
        for (int rt = 0; rt < 2; ++rt) for (int ct = 0; ct < 8; ++ct) acc[rt][ct] = (floatx4){0,0,0,0};
        for (int kc = 0; kc < 4; ++kc)
            for (int ct = 0; ct < 8; ++ct) {
                short8 fb = *(const short8*)(W2F + (ct * 4 + kc) * 512 + lane * 8);
                acc[0][ct] = __builtin_amdgcn_mfma_f32_16x16x32_bf16(Af[0][kc], fb, acc[0][ct], 0, 0, 0);
                acc[1][ct] = __builtin_amdgcn_mfma_f32_16x16x32_bf16(Af[1][kc], fb, acc[1][ct], 0, 0, 0);
            }
        for (int ct = 0; ct < 8; ++ct) {
            int col = ct * 16 + l16;
            float bb = b2g[col];
            for (int rt = 0; rt < 2; ++rt)
                for (int r = 0; r < 4; ++r) {
                    int row = rt * 16 + quad * 4 + r;
                    buf1[row * BUFW + col] = f2b(gelu_f(acc[rt][ct][r] + bb));
                }
        }
    }

    // ---- stage 3: buf1 @ W3 + b3 -> masked mean -> nm ----
    {
        short8 Af[2][4];
        for (int kc = 0; kc < 4; ++kc) {
            Af[0][kc] = *(const short8*)&buf1[l16 * BUFW + kc * 32 + ko];
            Af[1][kc] = *(const short8*)&buf1[(16 + l16) * BUFW + kc * 32 + ko];
        }
        floatx4 acc[2][8];
        for (int rt = 0; rt < 2; ++rt) for (int ct = 0; ct < 8; ++ct) acc[rt][ct] = (floatx4){0,0,0,0};
        for (int kc = 0; kc < 4; ++kc)
            for (int ct = 0; ct < 8; ++ct) {
                short8 fb = *(const short8*)(W3F + (ct * 4 + kc) * 512 + lane * 8);
                acc[0][ct] = __builtin_amdgcn_mfma_f32_16x16x32_bf16(Af[0][kc], fb, acc[0][ct], 0, 0, 0);
                acc[1][ct] = __builtin_amdgcn_mfma_f32_16x16x32_bf16(Af[1][kc], fb, acc[1][ct], 0, 0, 0);
            }
        for (int ct = 0; ct < 8; ++ct) {
            int col = ct * 16 + l16;
            float bb = b3g[col];
            float cs = 0.0f;
            for (int rt = 0; rt < 2; ++rt)
                for (int r = 0; r < 4; ++r)
                    cs += (acc[rt][ct][r] + bb) * maskR[rt][r];
            cs += __shfl_xor(cs, 16, 64);
            cs += __shfl_xor(cs, 32, 64);
            if (lane < 16) Fv[NM_OFF + col] = cs;
        }
    }

    // ---- tail: LN1 -> FFN -> LN2 -> out ----
    {
        int c0 = lane, c1 = lane + 64;
        float xb0 = hVb[c0] + Fv[NM_OFF + c0];
        float xb1 = hVb[c1] + Fv[NM_OFF + c1];
        float s = xb0 + xb1, q = xb0 * xb0 + xb1 * xb1;
        for (int o = 32; o; o >>= 1) { s += __shfl_xor(s, o, 64); q += __shfl_xor(q, o, 64); }
        float m = s * (1.0f / 128.0f);
        float inv = 1.0f / sqrtf(q * (1.0f / 128.0f) - m * m + 1e-5f);
        float h0 = (xb0 - m) * inv * g1[c0] + be1[c0];
        float h1 = (xb1 - m) * inv * g1[c1] + be1[c1];
        Fv[c0] = h0; Fv[c1] = h1;

        // FFN1: coalesced WiF [c8][o][8]
        for (int j = 0; j < 8; ++j) {
            int o = lane + 64 * j;
            float sa = big[o], sb = 0.0f;
            for (int c8 = 0; c8 < 16; c8 += 2) {
                ushort8 v0 = *(const ushort8*)(WiF + c8 * 4096 + o * 8);
                ushort8 v1 = *(const ushort8*)(WiF + (c8 + 1) * 4096 + o * 8);
                sa += dot8(&Fv[c8 * 8], v0);
                sb += dot8(&Fv[c8 * 8 + 8], v1);
            }
            Fv[128 + o] = gelu_f(sa + sb);
        }

        // FFN2: coalesced WoF [o8][c][8]
        float d0a = bog[c0], d0b = 0.0f, d1a = bog[c1], d1b = 0.0f;
        for (int o8 = 0; o8 < 64; o8 += 2) {
            ushort8 v0  = *(const ushort8*)(WoF + o8 * 1024 + c0 * 8);
            ushort8 v0n = *(const ushort8*)(WoF + (o8 + 1) * 1024 + c0 * 8);
            ushort8 v1  = *(const ushort8*)(WoF + o8 * 1024 + c1 * 8);
            ushort8 v1n = *(const ushort8*)(WoF + (o8 + 1) * 1024 + c1 * 8);
            const float* gp = &Fv[128 + o8 * 8];
            d0a += dot8(gp, v0);  d0b += dot8(gp + 8, v0n);
            d1a += dot8(gp, v1);  d1b += dot8(gp + 8, v1n);
        }
        float y0 = h0 + d0a + d0b, y1 = h1 + d1a + d1b;
        float s2 = y0 + y1, q2 = y0 * y0 + y1 * y1;
        for (int o = 32; o; o >>= 1) { s2 += __shfl_xor(s2, o, 64); q2 += __shfl_xor(q2, o, 64); }
        float m2 = s2 * (1.0f / 128.0f);
        float inv2 = 1.0f / sqrtf(q2 * (1.0f / 128.0f) - m2 * m2 + 1e-5f);
        float mv = mask_V[site];
        out[site * 128 + c0] = ((y0 - m2) * inv2 * g2[c0] + be2[c0]) * mv;
        out[site * 128 + c1] = ((y1 - m2) * inv2 * g2[c1] + be2[c1]) * mv;
    }
}

extern "C" void kernel_launch(void* const* d_in, const int* in_sizes, int n_in,
                              void* d_out, int out_size, void* d_ws, size_t ws_size,
                              hipStream_t stream) {
    const float* h_V = (const float*)d_in[0];
    const float* h_E = (const float*)d_in[1];
    // d_in[2] = E_idx (int32, unused by reference)
    const float* Xn  = (const float*)d_in[3];
    const float* mV  = (const float*)d_in[4];
    const float* mA  = (const float*)d_in[5];
    const float* Wp  = (const float*)d_in[6];
    const float* bp  = (const float*)d_in[7];
    const float* W1  = (const float*)d_in[8];
    const float* b1  = (const float*)d_in[9];
    const float* W2  = (const float*)d_in[10];
    const float* b2  = (const float*)d_in[11];
    const float* W3  = (const float*)d_in[12];
    const float* b3  = (const float*)d_in[13];
    const float* Wi  = (const float*)d_in[14];
    const float* bi  = (const float*)d_in[15];
    const float* Wo  = (const float*)d_in[16];
    const float* bo  = (const float*)d_in[17];
    const float* g1  = (const float*)d_in[18];
    const float* be1 = (const float*)d_in[19];
    const float* g2  = (const float*)d_in[20];
    const float* be2 = (const float*)d_in[21];
    unsigned short* ws = (unsigned short*)d_ws;
    float* out = (float*)d_out;

    prep_kernel<<<960, 256, 0, stream>>>(W1, W2, W3, Wi, Wo, Wp, ws);
    main_kernel<<<(B_ * L_) / 2, 128, 0, stream>>>(h_V, h_E, Xn, mV, mA, bp,
                                                   b1, b2, b3, bi, bo,
                                                   g1, be1, g2, be2, ws, out);
}